// Round 3
// baseline (53454.645 us; speedup 1.0000x reference)
//
#include <hip/hip_runtime.h>

typedef double rl;
#define NT 256
#define NSV 71
#define LDA 128
#define LDV 72
#define SML 25
#define VOCAB 128000

// fp32 LAPACK constants (reference is numpy sgesdd in float32)
#define EPS32 1.1920928955078125e-7
#define UNFL32 1.17549435e-38

// g_ws offsets (doubles)
#define O_CAR   0
#define O_COLS  4608
#define O_VEC   4800
#define O_MA    5120
#define O_MB    14336
#define O_MU    23552
#define O_MQ    32768
#define O_MVT   41984
#define O_SUB   47168
#define O_SVTB  52352
#define O_U2    57536
#define O_VT2   62720
#define O_QU    67904
#define O_QV    73088
#define O_TB    78272
// end 83456

__device__ double g_ws[84000];

struct Sh {
  rl d[72], e[72], tq[72], tp[72], rc[72], rs[72];
  rl dsig[72], zz[72], zh[72], sigm[72], vals[72];
  rl ta[72], tb[72];
  rl b1[72], b2[72], b3[72], b4[72];
  int srcU[72], srcVT[72], perm[72];
  int ia[72], ib[72], ic[72];
  int opk[12], opf[12], opa[12], opb[12], opq[12];
  rl sc[8];
  int si[8];
};

__device__ __forceinline__ rl d_sign(rl a, rl b){ return (b >= 0.0) ? fabs(a) : -fabs(a); }
__device__ __forceinline__ rl dlapy2(rl x, rl y){
  rl ax=fabs(x), ay=fabs(y);
  rl w = ax>ay?ax:ay, z = ax>ay?ay:ax;
  if(z==0.0) return w;
  rl t = z/w; return w*sqrt(1.0+t*t);
}
// LAPACK >= 3.10 dlartg convention (modern OpenBLAS)
__device__ void dlartg(rl f, rl g, rl* cs, rl* sn, rl* r){
  if(g==0.0){ *cs=1.0; *sn=0.0; *r=f; }
  else if(f==0.0){ *cs=0.0; *sn=d_sign(1.0,g); *r=fabs(g); }
  else{
    rl dd = sqrt(f*f+g*g);
    *cs = fabs(f)/dd;
    *r  = d_sign(dd, f);
    *sn = g/(*r);
  }
}

__device__ void dlas2(rl f, rl g, rl h, rl* ssmin, rl* ssmax){
  rl fa=fabs(f), ga=fabs(g), ha=fabs(h);
  rl fhmn=fmin(fa,ha), fhmx=fmax(fa,ha);
  if(fhmn==0.0){
    *ssmin=0.0;
    if(fhmx==0.0) *ssmax=ga;
    else { rl mx=fmax(fhmx,ga), mn=fmin(fhmx,ga); rl q=mn/mx; *ssmax=mx*sqrt(1.0+q*q); }
  } else {
    if(ga < fhmx){
      rl as=1.0+fhmn/fhmx, at=(fhmx-fhmn)/fhmx;
      rl au=(ga/fhmx); au=au*au;
      rl c=2.0/(sqrt(as*as+au)+sqrt(at*at+au));
      *ssmin=fhmn*c; *ssmax=fhmx/c;
    } else {
      rl au=fhmx/ga;
      if(au==0.0){ *ssmin=(fhmn*fhmx)/ga; *ssmax=ga; }
      else{
        rl as=1.0+fhmn/fhmx, at=(fhmx-fhmn)/fhmx;
        rl c=1.0/(sqrt(1.0+(as*au)*(as*au))+sqrt(1.0+(at*au)*(at*au)));
        *ssmin=(fhmn*c)*au; *ssmin=*ssmin+*ssmin;
        *ssmax=ga/(c+c);
      }
    }
  }
}

__device__ void dlasv2(rl f, rl g, rl h, rl* ssmin, rl* ssmax, rl* snr, rl* csr, rl* snl, rl* csl){
  rl ft=f, fa=fabs(f), ht=h, ha=fabs(h);
  int pmax=1;
  bool swp = (ha > fa);
  if(swp){ pmax=3; rl t=ft; ft=ht; ht=t; t=fa; fa=ha; ha=t; }
  rl gt=g, ga=fabs(g);
  rl clt=0, crt=0, slt=0, srt=0;
  if(ga==0.0){ *ssmin=ha; *ssmax=fa; clt=1.0; crt=1.0; slt=0.0; srt=0.0; }
  else{
    bool gasmal=true;
    if(ga > fa){
      pmax=2;
      if((fa/ga) < EPS32){
        gasmal=false;
        *ssmax=ga;
        if(ha>1.0) *ssmin=fa/(ga/ha); else *ssmin=(fa/ga)*ha;
        clt=1.0; slt=ht/gt; srt=1.0; crt=ft/gt;
      }
    }
    if(gasmal){
      rl dd=fa-ha;
      rl lv = (dd==fa) ? 1.0 : dd/fa;
      rl mq = gt/ft;
      rl tv = 2.0-lv;
      rl mm = mq*mq, tt = tv*tv;
      rl sv = sqrt(tt+mm);
      rl rv = (lv==0.0) ? fabs(mq) : sqrt(lv*lv+mm);
      rl a = 0.5*(sv+rv);
      *ssmin = ha/a; *ssmax = fa*a;
      rl t3;
      if(mm==0.0){
        if(lv==0.0) t3 = d_sign(2.0, ft)*d_sign(1.0, gt);
        else t3 = gt/d_sign(dd, ft) + mq/tv;
      } else {
        t3 = (mq/(sv+tv) + mq/(rv+lv))*(1.0+a);
      }
      rl l2 = sqrt(t3*t3+4.0);
      crt = 2.0/l2; srt = t3/l2;
      clt = (crt + srt*mq)/a;
      slt = (ht/ft)*srt/a;
    }
  }
  if(swp){ *csl=srt; *snl=crt; *csr=slt; *snr=clt; }
  else  { *csl=clt; *snl=slt; *csr=crt; *snr=srt; }
  rl tsign=1.0;
  if(pmax==1) tsign = d_sign(1.0,*csr)*d_sign(1.0,*csl)*d_sign(1.0,f);
  if(pmax==2) tsign = d_sign(1.0,*snr)*d_sign(1.0,*csl)*d_sign(1.0,g);
  if(pmax==3) tsign = d_sign(1.0,*snr)*d_sign(1.0,*snl)*d_sign(1.0,h);
  *ssmax = d_sign(*ssmax, tsign);
  *ssmin = d_sign(*ssmin, tsign*d_sign(1.0,f)*d_sign(1.0,h));
}

__device__ void app_left(rl* A, int ld, int r0, int m, int c0, int n, const rl* vbase, rl tau, int tid){
  for(int c=c0+tid; c<n; c+=NT){
    rl* col = A + (size_t)ld*c;
    rl w = col[r0];
    for(int r=r0+1;r<m;++r) w += col[r]*vbase[r];
    w *= tau;
    col[r0] -= w;
    for(int r=r0+1;r<m;++r) col[r] -= w*vbase[r];
  }
}
__device__ void app_right(rl* A, int ld, int r0, int m, int c0, int n, const rl* vbase, int vstride, rl tau, int tid){
  for(int r=r0+tid; r<m; r+=NT){
    rl w = A[r + (size_t)ld*c0];
    for(int c=c0+1;c<n;++c) w += A[r + (size_t)ld*c]*vbase[(size_t)vstride*c];
    w *= tau;
    A[r + (size_t)ld*c0] -= w;
    for(int c=c0+1;c<n;++c) A[r + (size_t)ld*c] -= w*vbase[(size_t)vstride*c];
  }
}

// ---- dlasr variants (tid0 serial) ----
__device__ void lasr_LVF(rl* A, int ld, int lo, int hi, int nc, const rl* c, const rl* s){
  for(int j=0;j<hi-lo;++j){
    rl cj=c[j], sj=s[j];
    if(cj==1.0 && sj==0.0) continue;
    for(int k=0;k<nc;++k){
      size_t ci=(size_t)ld*k;
      rl t = A[(lo+j+1)+ci];
      A[(lo+j+1)+ci] = cj*t - sj*A[(lo+j)+ci];
      A[(lo+j)+ci]   = sj*t + cj*A[(lo+j)+ci];
    }
  }
}
__device__ void lasr_LVB(rl* A, int ld, int lo, int hi, int nc, const rl* c, const rl* s){
  for(int j=hi-lo-1;j>=0;--j){
    rl cj=c[j], sj=s[j];
    if(cj==1.0 && sj==0.0) continue;
    for(int k=0;k<nc;++k){
      size_t ci=(size_t)ld*k;
      rl t = A[(lo+j+1)+ci];
      A[(lo+j+1)+ci] = cj*t - sj*A[(lo+j)+ci];
      A[(lo+j)+ci]   = sj*t + cj*A[(lo+j)+ci];
    }
  }
}
__device__ void lasr_RVF(rl* A, int ld, int lo, int hi, int nr, const rl* c, const rl* s){
  for(int j=0;j<hi-lo;++j){
    rl cj=c[j], sj=s[j];
    if(cj==1.0 && sj==0.0) continue;
    for(int r=0;r<nr;++r){
      rl t = A[r+(size_t)ld*(lo+j+1)];
      A[r+(size_t)ld*(lo+j+1)] = cj*t - sj*A[r+(size_t)ld*(lo+j)];
      A[r+(size_t)ld*(lo+j)]   = sj*t + cj*A[r+(size_t)ld*(lo+j)];
    }
  }
}
__device__ void lasr_RVB(rl* A, int ld, int lo, int hi, int nr, const rl* c, const rl* s){
  for(int j=hi-lo-1;j>=0;--j){
    rl cj=c[j], sj=s[j];
    if(cj==1.0 && sj==0.0) continue;
    for(int r=0;r<nr;++r){
      rl t = A[r+(size_t)ld*(lo+j+1)];
      A[r+(size_t)ld*(lo+j+1)] = cj*t - sj*A[r+(size_t)ld*(lo+j)];
      A[r+(size_t)ld*(lo+j)]   = sj*t + cj*A[r+(size_t)ld*(lo+j)];
    }
  }
}

// ---- dbdsqr port (tid0 serial), rotation buffers from shared ----
__device__ void bdsqr(int n, rl* d, rl* e, rl* VT, int ldvt, int ncvt, rl* U, int ldu, int nru,
                      rl* rc1, rl* rs1, rl* rc2, rl* rs2){
  if(n==0) return;
  if(n>1){
    rl eps=EPS32, unfl=UNFL32;
    rl tolmul = fmax(10.0, fmin(100.0, pow(eps, -0.125)));
    rl tol = tolmul*eps;
    rl sminoa = fabs(d[0]);
    if(sminoa != 0.0){
      rl mu = sminoa;
      for(int i=1;i<n;++i){ mu = fabs(d[i])*(mu/(mu+fabs(e[i-1]))); sminoa=fmin(sminoa,mu); if(sminoa==0.0) break; }
    }
    sminoa = sminoa/sqrt((rl)n);
    rl thresh = fmax(tol*sminoa, (rl)(6*n*n)*unfl);
    int maxit = 6*n*n, iter=0;
    int mm = n-1, oldll=-2, oldm=-2, idir=0;
    rl cs, sn, r, oldcs, oldsn;
    while(mm > 0){
      if(iter > maxit) break;
      rl smax = fabs(d[mm]), smin = smax;
      int ll = -1;
      for(int lll=mm-1; lll>=0; --lll){
        rl abss=fabs(d[lll]), abse=fabs(e[lll]);
        if(abse <= thresh){ ll=lll; break; }
        smin = fmin(smin, abss);
        smax = fmax(smax, fmax(abss, abse));
      }
      if(ll == mm-1){ e[ll]=0.0; mm = mm-1; continue; }
      if(ll >= 0) e[ll]=0.0;
      int lo = ll+1;
      if(mm == lo+1){
        rl sigmn, sigmx, sinr, cosr, sinl, cosl;
        dlasv2(d[lo], e[lo], d[mm], &sigmn, &sigmx, &sinr, &cosr, &sinl, &cosl);
        d[lo]=sigmx; d[mm]=sigmn; e[lo]=0.0;
        if(ncvt>0){
          for(int c=0;c<ncvt;++c){
            size_t ci=(size_t)ldvt*c;
            rl x=VT[lo+ci], y=VT[mm+ci];
            VT[lo+ci]=cosr*x+sinr*y; VT[mm+ci]=cosr*y-sinr*x;
          }
        }
        if(nru>0){
          for(int rr=0;rr<nru;++rr){
            rl x=U[rr+(size_t)ldu*lo], y=U[rr+(size_t)ldu*mm];
            U[rr+(size_t)ldu*lo]=cosl*x+sinl*y; U[rr+(size_t)ldu*mm]=cosl*y-sinl*x;
          }
        }
        mm -= 2;
        continue;
      }
      if(lo > oldm || mm < oldll) idir = (fabs(d[lo]) >= fabs(d[mm])) ? 1 : 2;
      rl sminl=0.0;
      int conv=0;
      if(idir==1){
        if(fabs(e[mm-1]) <= tol*fabs(d[mm])){ e[mm-1]=0.0; conv=1; }
        if(!conv){
          rl mu=fabs(d[lo]); sminl=mu;
          for(int lll=lo; lll<mm; ++lll){
            if(fabs(e[lll]) <= tol*mu){ e[lll]=0.0; conv=1; break; }
            mu = fabs(d[lll+1])*(mu/(mu+fabs(e[lll])));
            sminl = fmin(sminl, mu);
          }
        }
      } else {
        if(fabs(e[lo]) <= tol*fabs(d[lo])){ e[lo]=0.0; conv=1; }
        if(!conv){
          rl mu=fabs(d[mm]); sminl=mu;
          for(int lll=mm-1; lll>=lo; --lll){
            if(fabs(e[lll]) <= tol*mu){ e[lll]=0.0; conv=1; break; }
            mu = fabs(d[lll])*(mu/(mu+fabs(e[lll])));
            sminl = fmin(sminl, mu);
          }
        }
      }
      if(conv) continue;
      oldll=lo; oldm=mm;
      rl shift=0.0, rr_;
      if(!((rl)n*tol*(sminl/smax) <= fmax(eps, 0.01*tol))){
        rl sll;
        if(idir==1){ sll=fabs(d[lo]); dlas2(d[mm-1], e[mm-1], d[mm], &shift, &rr_); }
        else { sll=fabs(d[mm]); dlas2(d[lo], e[lo], d[lo+1], &shift, &rr_); }
        if(sll > 0.0){ rl q=shift/sll; if(q*q < eps) shift=0.0; }
      }
      iter += mm-lo;
      if(shift==0.0){
        if(idir==1){
          cs=1.0; oldcs=1.0;
          for(int i=lo;i<mm;++i){
            dlartg(d[i]*cs, e[i], &cs, &sn, &r);
            if(i>lo) e[i-1] = oldsn*r;
            dlartg(oldcs*r, d[i+1]*sn, &oldcs, &oldsn, &d[i]);
            rc1[i-lo]=cs; rs1[i-lo]=sn; rc2[i-lo]=oldcs; rs2[i-lo]=oldsn;
          }
          rl h = d[mm]*cs; d[mm]=h*oldcs; e[mm-1]=h*oldsn;
          if(ncvt>0) lasr_LVF(VT, ldvt, lo, mm, ncvt, rc1, rs1);
          if(nru>0)  lasr_RVF(U, ldu, lo, mm, nru, rc2, rs2);
          if(fabs(e[mm-1]) <= thresh) e[mm-1]=0.0;
        } else {
          cs=1.0; oldcs=1.0;
          for(int i=mm;i>lo;--i){
            dlartg(d[i]*cs, e[i-1], &cs, &sn, &r);
            if(i<mm) e[i] = oldsn*r;
            dlartg(oldcs*r, d[i-1]*sn, &oldcs, &oldsn, &d[i]);
            int j=i-lo-1;
            rc1[j]=cs; rs1[j]=-sn; rc2[j]=oldcs; rs2[j]=-oldsn;
          }
          rl h = d[lo]*cs; d[lo]=h*oldcs; e[lo]=h*oldsn;
          if(ncvt>0) lasr_LVB(VT, ldvt, lo, mm, ncvt, rc2, rs2);
          if(nru>0)  lasr_RVB(U, ldu, lo, mm, nru, rc1, rs1);
          if(fabs(e[lo]) <= thresh) e[lo]=0.0;
        }
      } else {
        if(idir==1){
          rl f = (fabs(d[lo]) - shift)*(d_sign(1.0, d[lo]) + shift/d[lo]);
          rl g = e[lo];
          rl cosr,sinr,cosl,sinl;
          for(int i=lo;i<mm;++i){
            dlartg(f, g, &cosr, &sinr, &r);
            if(i>lo) e[i-1]=r;
            f = cosr*d[i] + sinr*e[i];
            e[i] = cosr*e[i] - sinr*d[i];
            g = sinr*d[i+1];
            d[i+1] = cosr*d[i+1];
            dlartg(f, g, &cosl, &sinl, &r);
            d[i]=r;
            f = cosl*e[i] + sinl*d[i+1];
            d[i+1] = cosl*d[i+1] - sinl*e[i];
            if(i<mm-1){ g = sinl*e[i+1]; e[i+1] = cosl*e[i+1]; }
            rc1[i-lo]=cosr; rs1[i-lo]=sinr; rc2[i-lo]=cosl; rs2[i-lo]=sinl;
          }
          e[mm-1]=f;
          if(ncvt>0) lasr_LVF(VT, ldvt, lo, mm, ncvt, rc1, rs1);
          if(nru>0)  lasr_RVF(U, ldu, lo, mm, nru, rc2, rs2);
          if(fabs(e[mm-1]) <= thresh) e[mm-1]=0.0;
        } else {
          rl f = (fabs(d[mm]) - shift)*(d_sign(1.0, d[mm]) + shift/d[mm]);
          rl g = e[mm-1];
          rl cosr,sinr,cosl,sinl;
          for(int i=mm;i>lo;--i){
            dlartg(f, g, &cosr, &sinr, &r);
            if(i<mm) e[i]=r;
            f = cosr*d[i] + sinr*e[i-1];
            e[i-1] = cosr*e[i-1] - sinr*d[i];
            g = sinr*d[i-1];
            d[i-1] = cosr*d[i-1];
            dlartg(f, g, &cosl, &sinl, &r);
            d[i]=r;
            f = cosl*e[i-1] + sinl*d[i-1];
            d[i-1] = cosl*d[i-1] - sinl*e[i-1];
            if(i>lo+1){ g = sinl*e[i-2]; e[i-2] = cosl*e[i-2]; }
            int j=i-lo-1;
            rc1[j]=cosr; rs1[j]=-sinr; rc2[j]=cosl; rs2[j]=-sinl;
          }
          e[lo]=f;
          if(ncvt>0) lasr_LVB(VT, ldvt, lo, mm, ncvt, rc2, rs2);
          if(nru>0)  lasr_RVB(U, ldu, lo, mm, nru, rc1, rs1);
          if(fabs(e[lo]) <= thresh) e[lo]=0.0;
        }
      }
    }
  }
  for(int i=0;i<n;++i){
    if(d[i] < 0.0){
      d[i] = -d[i];
      if(ncvt>0) for(int c=0;c<ncvt;++c) VT[i+(size_t)ldvt*c] = -VT[i+(size_t)ldvt*c];
    }
  }
  for(int i=0;i<n-1;++i){
    int isub=0; rl smin=d[0];
    for(int j=1;j<n-i;++j){ if(d[j] <= smin){ isub=j; smin=d[j]; } }
    int tgt=n-1-i;
    if(isub != tgt){
      d[isub]=d[tgt]; d[tgt]=smin;
      if(ncvt>0) for(int c=0;c<ncvt;++c){ size_t ci=(size_t)ldvt*c; rl t=VT[isub+ci]; VT[isub+ci]=VT[tgt+ci]; VT[tgt+ci]=t; }
      if(nru>0)  for(int rr=0;rr<nru;++rr){ rl t=U[rr+(size_t)ldu*isub]; U[rr+(size_t)ldu*isub]=U[rr+(size_t)ldu*tgt]; U[rr+(size_t)ldu*tgt]=t; }
    }
  }
}

// ---- leaf: dlasdq ----
__device__ void leaf_exec(int f, int n, int sqre, Sh* sh, int tid){
  rl* SVTB = g_ws + O_SVTB; rl* SUB = g_ws + O_SUB;
  if(tid==0){
    rl* dd = sh->d + f; rl* ee = sh->e + f;
    int np = n + sqre;
    if(sqre==1){
      rl cs,snv,rv;
      for(int i=0;i<n;++i){
        dlartg(dd[i], ee[i], &cs, &snv, &rv);
        dd[i]=rv;
        if(i<n-1){ ee[i]=snv*dd[i+1]; dd[i+1]=cs*dd[i+1]; }
        else ee[i]=0.0;
        sh->b1[i]=cs; sh->b2[i]=snv;
      }
      for(int j=0;j<n;++j){
        rl cj=sh->b1[j], sj=sh->b2[j];
        for(int k=0;k<np;++k){
          size_t ci=(size_t)LDV*(f+k);
          rl t=SVTB[(f+j+1)+ci];
          SVTB[(f+j+1)+ci]=cj*t - sj*SVTB[(f+j)+ci];
          SVTB[(f+j)+ci]  =sj*t + cj*SVTB[(f+j)+ci];
        }
      }
      for(int i=0;i<n-1;++i){
        dlartg(dd[i], ee[i], &cs, &snv, &rv);
        dd[i]=rv; ee[i]=snv*dd[i+1]; dd[i+1]=cs*dd[i+1];
        sh->b1[i]=cs; sh->b2[i]=snv;
      }
      for(int j=0;j<n-1;++j){
        rl cj=sh->b1[j], sj=sh->b2[j];
        for(int rr=0;rr<n;++rr){
          rl t=SUB[(f+rr)+(size_t)LDV*(f+j+1)];
          SUB[(f+rr)+(size_t)LDV*(f+j+1)]=cj*t - sj*SUB[(f+rr)+(size_t)LDV*(f+j)];
          SUB[(f+rr)+(size_t)LDV*(f+j)]  =sj*t + cj*SUB[(f+rr)+(size_t)LDV*(f+j)];
        }
      }
    }
    bdsqr(n, dd, ee, SVTB + f + (size_t)LDV*f, LDV, np, SUB + f + (size_t)LDV*f, LDV, n,
          sh->b1, sh->b2, sh->b3, sh->b4);
  }
  __syncthreads();
}

// ---- D&C merge (dlasd1/2/3) ----
__device__ void lasd1_merge(int f, int nl, int nr, int sqre, Sh* sh, int tid){
  rl* SUB = g_ws + O_SUB; rl* SVTB = g_ws + O_SVTB;
  rl* U2 = g_ws + O_U2; rl* VT2 = g_ws + O_VT2; rl* QU = g_ws + O_QU; rl* QV = g_ws + O_QV;
  int n = nl+nr+1, m = n+sqre;
  if(tid==0){
    rl alpha = sh->d[f+nl], beta = sh->e[f+nl];
    sh->vals[0]=0.0;
    sh->zz[0] = alpha*SVTB[(f+nl)+(size_t)LDV*(f+nl)];
    sh->srcU[0]=-1; sh->srcVT[0]=f+nl;
    for(int i=0;i<nl;++i){
      sh->vals[1+i]=sh->d[f+i];
      sh->zz[1+i]=alpha*SVTB[(f+i)+(size_t)LDV*(f+nl)];
      sh->srcU[1+i]=f+i; sh->srcVT[1+i]=f+i;
    }
    for(int j=0;j<nr;++j){
      sh->vals[1+nl+j]=sh->d[f+nl+1+j];
      sh->zz[1+nl+j]=beta*SVTB[(f+nl+1+j)+(size_t)LDV*(f+nl+1)];
      sh->srcU[1+nl+j]=f+nl+1+j; sh->srcVT[1+nl+j]=f+nl+1+j;
    }
    sh->sc[0]=alpha; sh->sc[1]=beta;
    if(sqre==1){
      rl zM = beta*SVTB[(f+n)+(size_t)LDV*(f+nl+1)];
      rl c,s,r2;
      dlartg(sh->zz[0], zM, &c, &s, &r2);
      sh->zz[0]=r2; sh->sc[2]=c; sh->sc[3]=s;
    }
  }
  __syncthreads();
  if(sqre==1){
    rl c=sh->sc[2], s=sh->sc[3];
    int ra=f+nl, rb=f+n;
    for(int k=tid;k<m;k+=NT){
      size_t ci=(size_t)LDV*(f+k);
      rl a=SVTB[ra+ci], b=SVTB[rb+ci];
      SVTB[ra+ci]=c*a+s*b; SVTB[rb+ci]=-s*a+c*b;
    }
  }
  __syncthreads();
  if(tid==0){
    rl maxd=0.0; for(int i=0;i<n;++i) maxd=fmax(maxd,fabs(sh->vals[i]));
    rl tol = 8.0*EPS32*fmax(maxd, fmax(fabs(sh->sc[0]), fabs(sh->sc[1])));
    int nds=0;
    sh->ic[nds++]=0;
    for(int i=1;i<n;++i) if(fabs(sh->zz[i]) > tol) sh->ic[nds++]=i;
    for(int a=1;a<nds;++a){
      int key=sh->ic[a]; rl kv=sh->vals[key]; int b=a-1;
      while(b>=1 && sh->vals[sh->ic[b]] > kv){ sh->ic[b+1]=sh->ic[b]; --b; }
      sh->ic[b+1]=key;
    }
    int K=nds, pos=nds;
    for(int i=1;i<n;++i) if(fabs(sh->zz[i]) <= tol) sh->ic[pos++]=i;
    // sort deflated tail ascending by value
    for(int a=K+1;a<n;++a){
      int key=sh->ic[a]; rl kv=sh->vals[key]; int b=a-1;
      while(b>=K && sh->vals[sh->ic[b]] > kv){ sh->ic[b+1]=sh->ic[b]; --b; }
      sh->ic[b+1]=key;
    }
    for(int t=0;t<n;++t){ sh->ta[t]=sh->vals[t]; sh->tb[t]=sh->zz[t]; sh->ia[t]=sh->srcU[t]; sh->ib[t]=sh->srcVT[t]; }
    for(int t=0;t<n;++t){
      int p=sh->ic[t];
      sh->dsig[t]=sh->ta[p]; sh->zz[t]=sh->tb[p]; sh->srcU[t]=sh->ia[p]; sh->srcVT[t]=sh->ib[p];
    }
    rl rho=0.0; for(int t=0;t<K;++t){ rl zv=sh->zz[t]; rho += zv*zv; }
    sh->sc[4]=rho;
    sh->si[0]=K; sh->si[1]=n; sh->si[2]=m; sh->si[3]=f; sh->si[4]=nl;
  }
  __syncthreads();
  int K=sh->si[0], n_=sh->si[1], m_=sh->si[2], f_=sh->si[3], nl_=sh->si[4];
  for(int w=tid; w<n_*n_; w+=NT){
    int col=w/n_, row=w-col*n_;
    int su=sh->srcU[col];
    rl v;
    if(su<0) v = (row==nl_) ? 1.0 : 0.0;
    else v = SUB[(f_+row)+(size_t)LDV*su];
    U2[row+(size_t)LDV*col]=v;
  }
  for(int w=tid; w<n_*m_; w+=NT){
    int row=w/m_, col=w-row*m_;
    VT2[row+(size_t)LDV*col] = SVTB[sh->srcVT[row]+(size_t)LDV*(f_+col)];
  }
  __syncthreads();
  rl rho=sh->sc[4];
  for(int j=tid;j<K;j+=NT){
    rl lo=sh->dsig[j];
    rl hi=(j<K-1)? sh->dsig[j+1] : sqrt(sh->dsig[K-1]*sh->dsig[K-1]+rho);
    for(int it=0; it<130; ++it){
      rl mid=0.5*(lo+hi);
      if(mid<=lo || mid>=hi) break;
      rl g=1.0;
      for(int i2=0;i2<K;++i2){
        rl zi=sh->zz[i2];
        g += zi*zi/((sh->dsig[i2]-mid)*(sh->dsig[i2]+mid));
      }
      if(g<0.0) lo=mid; else hi=mid;
    }
    sh->sigm[j]=0.5*(lo+hi);
  }
  __syncthreads();
  for(int i2=tid;i2<K;i2+=NT){
    rl di=sh->dsig[i2];
    rl p=(di - sh->sigm[K-1])*(di + sh->sigm[K-1]);
    for(int j=0;j<i2;++j)
      p *= (di - sh->sigm[j])*(di + sh->sigm[j])/((di - sh->dsig[j])*(di + sh->dsig[j]));
    for(int j=i2;j<K-1;++j)
      p *= (di - sh->sigm[j])*(di + sh->sigm[j])/((di - sh->dsig[j+1])*(di + sh->dsig[j+1]));
    sh->zh[i2] = d_sign(sqrt(fabs(p)), sh->zz[i2]);
  }
  __syncthreads();
  for(int j=tid;j<K;j+=NT){
    rl sj=sh->sigm[j];
    rl nu=0.0, nv=0.0;
    for(int i2=0;i2<K;++i2){
      rl di=sh->dsig[i2];
      rl vv=sh->zh[i2]/((di-sj)*(di+sj));
      rl uu=(i2==0)? -1.0 : di*vv;
      QV[i2+(size_t)LDV*j]=vv; nv+=vv*vv;
      QU[i2+(size_t)LDV*j]=uu; nu+=uu*uu;
    }
    nu=1.0/sqrt(nu); nv=1.0/sqrt(nv);
    for(int i2=0;i2<K;++i2){ QV[i2+(size_t)LDV*j]*=nv; QU[i2+(size_t)LDV*j]*=nu; }
  }
  __syncthreads();
  if(tid==0){
    int nd2=n_-K;
    for(int t=0;t<nd2;++t) sh->ia[t]=K+t;   // deflated (ascending by dsig already)
    int ps=K-1, pd=nd2-1;                    // merge descending: secular desc = sigm[K-1..0]; deflated desc = ia[nd2-1..0]
    int t=0;
    while(t<n_){
      rl vs = (ps>=0)? sh->sigm[ps] : -1.0;
      rl vd = (pd>=0)? sh->dsig[sh->ia[pd]] : -1.0;
      if(vs >= vd){ sh->perm[t]=ps; sh->vals[t]=vs; --ps; }
      else { sh->perm[t]=1000+sh->ia[pd]; sh->vals[t]=vd; --pd; }
      ++t;
    }
    for(int q=0;q<n_;++q) sh->d[f_+q]=sh->vals[q];
  }
  __syncthreads();
  for(int w=tid; w<n_*n_; w+=NT){
    int t=w/n_, row=w-t*n_;
    int src=sh->perm[t];
    rl acc;
    if(src>=1000) acc = U2[row+(size_t)LDV*(src-1000)];
    else{
      acc=0.0;
      for(int i2=0;i2<K;++i2) acc += U2[row+(size_t)LDV*i2]*QU[i2+(size_t)LDV*src];
    }
    SUB[(f_+row)+(size_t)LDV*(f_+t)] = acc;
  }
  for(int w=tid; w<n_*m_; w+=NT){
    int t=w/m_, col=w-t*m_;
    int src=sh->perm[t];
    rl acc;
    if(src>=1000) acc = VT2[(src-1000)+(size_t)LDV*col];
    else{
      acc=0.0;
      for(int i2=0;i2<K;++i2) acc += QV[i2+(size_t)LDV*src]*VT2[i2+(size_t)LDV*col];
    }
    SVTB[(f_+t)+(size_t)LDV*(f_+col)] = acc;
  }
  __syncthreads();
}

// ---- dlasd0: iterative post-order over the D&C tree ----
__device__ void run_dc(int n, Sh* sh, int tid){
  if(tid==0){
    int sf[12], sn2[12], sq[12], sv[12]; int sp=0, no=0;
    sf[0]=0; sn2[0]=n; sq[0]=0; sv[0]=0; sp=1;
    while(sp>0){
      --sp;
      int f=sf[sp], nn=sn2[sp], q=sq[sp], v=sv[sp];
      if(nn<=SML){ sh->opk[no]=0; sh->opf[no]=f; sh->opa[no]=nn; sh->opq[no]=q; ++no; }
      else if(v==0){
        int nl=nn/2, nr=nn-nl-1;
        sf[sp]=f; sn2[sp]=nn; sq[sp]=q; sv[sp]=1; ++sp;
        sf[sp]=f+nl+1; sn2[sp]=nr; sq[sp]=q; sv[sp]=0; ++sp;
        sf[sp]=f; sn2[sp]=nl; sq[sp]=1; sv[sp]=0; ++sp;
      } else {
        int nl=nn/2, nr=nn-nl-1;
        sh->opk[no]=1; sh->opf[no]=f; sh->opa[no]=nl; sh->opb[no]=nr; sh->opq[no]=q; ++no;
      }
    }
    sh->si[6]=no;
  }
  __syncthreads();
  int no=sh->si[6];
  for(int o=0;o<no;++o){
    if(sh->opk[o]==0) leaf_exec(sh->opf[o], sh->opa[o], sh->opq[o], sh, tid);
    else lasd1_merge(sh->opf[o], sh->opa[o], sh->opb[o], sh->opq[o], sh, tid);
  }
}

__device__ void dbdsdc_U(int n, Sh* sh, int tid){
  rl* SUB = g_ws + O_SUB; rl* SVTB = g_ws + O_SVTB;
  for(int w=tid; w<LDV*LDV; w+=NT){ int c=w/LDV, r2=w-c*LDV; rl v=(r2==c)?1.0:0.0; SUB[w]=v; SVTB[w]=v; }
  __syncthreads();
  if(n <= SML) leaf_exec(0, n, 0, sh, tid);
  else run_dc(n, sh, tid);
}

__device__ void dbdsdc_L(int n, Sh* sh, int tid){
  if(tid==0){
    for(int i=0;i<n-1;++i){
      rl cs,snv,rv;
      dlartg(sh->d[i], sh->e[i], &cs,&snv,&rv);
      sh->d[i]=rv; sh->e[i]=snv*sh->d[i+1]; sh->d[i+1]=cs*sh->d[i+1];
      sh->rc[i]=cs; sh->rs[i]=snv;
    }
  }
  __syncthreads();
  dbdsdc_U(n, sh, tid);
  rl* SUB = g_ws + O_SUB;
  for(int c=tid;c<n;c+=NT){
    size_t ci=(size_t)LDV*c;
    for(int k=n-2;k>=0;--k){
      rl a=SUB[k+ci], b=SUB[k+1+ci];
      SUB[k+ci]  = sh->rc[k]*a - sh->rs[k]*b;
      SUB[k+1+ci]= sh->rs[k]*a + sh->rc[k]*b;
    }
  }
  __syncthreads();
}

// ---- Householder helpers ----
__device__ void gen_reflect_col(rl* A, int ld, int i, int r0, int m, rl* outBeta, rl* outTau, Sh* sh, int tid){
  if(tid==0){
    rl alpha=A[r0+(size_t)ld*i];
    rl xs=0.0; for(int r=r0+1;r<m;++r){ rl v=A[r+(size_t)ld*i]; xs+=v*v; }
    rl xn=sqrt(xs);
    rl beta, tau, scl; int doscale;
    if(xn==0.0){ tau=0.0; beta=alpha; scl=0.0; doscale=0; }
    else{ beta=-d_sign(dlapy2(alpha,xn),alpha); tau=(beta-alpha)/beta; scl=1.0/(alpha-beta); doscale=1; }
    sh->sc[5]=beta; sh->sc[6]=tau; sh->sc[7]=scl; sh->si[5]=doscale;
  }
  __syncthreads();
  if(sh->si[5]) for(int r=r0+1+tid;r<m;r+=NT) A[r+(size_t)ld*i]*=sh->sc[7];
  __syncthreads();
  if(tid==0){ *outBeta=sh->sc[5]; *outTau=sh->sc[6]; }
}
__device__ void gen_reflect_row(rl* A, int ld, int i, int c0, int n, rl* outBeta, rl* outTau, Sh* sh, int tid){
  if(tid==0){
    rl alpha=A[i+(size_t)ld*c0];
    rl xs=0.0; for(int c=c0+1;c<n;++c){ rl v=A[i+(size_t)ld*c]; xs+=v*v; }
    rl xn=sqrt(xs);
    rl beta, tau, scl; int doscale;
    if(xn==0.0){ tau=0.0; beta=alpha; scl=0.0; doscale=0; }
    else{ beta=-d_sign(dlapy2(alpha,xn),alpha); tau=(beta-alpha)/beta; scl=1.0/(alpha-beta); doscale=1; }
    sh->sc[5]=beta; sh->sc[6]=tau; sh->sc[7]=scl; sh->si[5]=doscale;
  }
  __syncthreads();
  if(sh->si[5]) for(int c=c0+1+tid;c<n;c+=NT) A[i+(size_t)ld*c]*=sh->sc[7];
  __syncthreads();
  if(tid==0){ *outBeta=sh->sc[5]; *outTau=sh->sc[6]; }
}

__device__ void gebd2_upper(rl* A, int ld, int m, int n, Sh* sh, int tid){
  for(int i=0;i<n;++i){
    gen_reflect_col(A, ld, i, i, m, &sh->d[i], &sh->tq[i], sh, tid);
    __syncthreads();
    if(sh->tq[i]!=0.0) app_left(A, ld, i, m, i+1, n, A+(size_t)ld*i, sh->tq[i], tid);
    __syncthreads();
    if(i<n-1){
      gen_reflect_row(A, ld, i, i+1, n, &sh->e[i], &sh->tp[i], sh, tid);
      __syncthreads();
      if(sh->tp[i]!=0.0) app_right(A, ld, i+1, m, i+1, n, A+i, ld, sh->tp[i], tid);
      __syncthreads();
    } else { if(tid==0) sh->tp[i]=0.0; __syncthreads(); }
  }
}
__device__ void gebd2_lower(rl* A, int ld, int m, int n, Sh* sh, int tid){
  for(int i=0;i<m;++i){
    gen_reflect_row(A, ld, i, i, n, &sh->d[i], &sh->tp[i], sh, tid);
    __syncthreads();
    if(sh->tp[i]!=0.0) app_right(A, ld, i+1, m, i, n, A+i, ld, sh->tp[i], tid);
    __syncthreads();
    if(i<m-1){
      gen_reflect_col(A, ld, i, i+1, m, &sh->e[i], &sh->tq[i], sh, tid);
      __syncthreads();
      if(sh->tq[i]!=0.0) app_left(A, ld, i+1, m, i+1, n, A+(size_t)ld*i, sh->tq[i], tid);
      __syncthreads();
    }
  }
}
__device__ void gelq2(rl* A, int ld, int m, int n, Sh* sh, int tid){
  for(int i=0;i<m;++i){
    rl beta, tau;
    gen_reflect_row(A, ld, i, i, n, &beta, &tau, sh, tid);
    if(tid==0){ sh->rs[i]=sh->sc[6]; A[i+(size_t)ld*i]=sh->sc[5]; }
    __syncthreads();
    if(i<m-1 && sh->rs[i]!=0.0) app_right(A, ld, i+1, m, i, n, A+i, ld, sh->rs[i], tid);
    __syncthreads();
  }
}

// ---- per-shape drivers ----
__device__ void svd_tall(Sh* sh, int tid){ // 128 x 71
  rl* MA=g_ws+O_MA; rl* MB=g_ws+O_MB; rl* MU=g_ws+O_MU; rl* MVT=g_ws+O_MVT;
  rl* SUB=g_ws+O_SUB; rl* SVTB=g_ws+O_SVTB;
  for(int w=tid;w<LDA*NSV;w+=NT) MB[w]=MA[w];
  __syncthreads();
  gebd2_upper(MB, LDA, 128, NSV, sh, tid);
  dbdsdc_U(NSV, sh, tid);
  for(int w=tid;w<128*NSV;w+=NT){ int c=w/128, r2=w-c*128; MU[r2+(size_t)LDA*c]=(r2<NSV)? SUB[r2+(size_t)LDV*c]:0.0; }
  __syncthreads();
  for(int i=NSV-1;i>=0;--i){
    if(sh->tq[i]!=0.0) app_left(MU, LDA, i, 128, 0, NSV, MB+(size_t)LDA*i, sh->tq[i], tid);
    __syncthreads();
  }
  for(int w=tid;w<LDV*NSV;w+=NT) MVT[w]=SVTB[w];
  __syncthreads();
  for(int i=NSV-2;i>=0;--i){
    if(sh->tp[i]!=0.0) app_right(MVT, LDV, 0, NSV, i+1, NSV, MB+i, LDA, sh->tp[i], tid);
    __syncthreads();
  }
}
__device__ void svd_mid(Sh* sh, int tid){ // 64 x 71
  rl* MA=g_ws+O_MA; rl* MB=g_ws+O_MB; rl* MU=g_ws+O_MU; rl* MVT=g_ws+O_MVT;
  rl* SUB=g_ws+O_SUB; rl* SVTB=g_ws+O_SVTB;
  for(int w=tid;w<LDA*NSV;w+=NT) MB[w]=MA[w];
  __syncthreads();
  gebd2_lower(MB, LDA, 64, NSV, sh, tid);
  dbdsdc_L(64, sh, tid);
  for(int w=tid;w<64*64;w+=NT){ int c=w/64, r2=w-c*64; MU[r2+(size_t)LDA*c]=SUB[r2+(size_t)LDV*c]; }
  __syncthreads();
  for(int i=62;i>=0;--i){
    if(sh->tq[i]!=0.0) app_left(MU, LDA, i+1, 64, 0, 64, MB+(size_t)LDA*i, sh->tq[i], tid);
    __syncthreads();
  }
  for(int w=tid;w<64*NSV;w+=NT){ int c=w/64, r2=w-c*64; MVT[r2+(size_t)LDV*c]=(c<64)? SVTB[r2+(size_t)LDV*c]:0.0; }
  __syncthreads();
  for(int i=63;i>=0;--i){
    if(sh->tp[i]!=0.0) app_right(MVT, LDV, 0, 64, i, NSV, MB+i, LDA, sh->tp[i], tid);
    __syncthreads();
  }
}
__device__ void svd_wide(int m, Sh* sh, int tid){ // m x 71, m in {2,4,8,16,32}
  rl* MA=g_ws+O_MA; rl* MB=g_ws+O_MB; rl* MU=g_ws+O_MU; rl* MQ=g_ws+O_MQ; rl* MVT=g_ws+O_MVT;
  rl* SUB=g_ws+O_SUB; rl* SVTB=g_ws+O_SVTB; rl* TB=g_ws+O_TB; rl* VT2=g_ws+O_VT2;
  for(int w=tid;w<LDA*NSV;w+=NT) MB[w]=MA[w];
  __syncthreads();
  gelq2(MB, LDA, m, NSV, sh, tid);
  for(int w=tid;w<m*NSV;w+=NT){ int c=w/m, r2=w-c*m; MQ[r2+(size_t)LDA*c]=(r2==c)?1.0:0.0; }
  __syncthreads();
  for(int j=m-1;j>=0;--j){
    if(sh->rs[j]!=0.0) app_right(MQ, LDA, 0, m, j, NSV, MB+j, LDA, sh->rs[j], tid);
    __syncthreads();
  }
  for(int w=tid;w<m*m;w+=NT){ int c=w/m, r2=w-c*m; TB[r2+(size_t)LDV*c]=(r2>=c)? MB[r2+(size_t)LDA*c]:0.0; }
  __syncthreads();
  gebd2_upper(TB, LDV, m, m, sh, tid);
  dbdsdc_U(m, sh, tid);
  for(int w=tid;w<m*m;w+=NT){ int c=w/m, r2=w-c*m; MU[r2+(size_t)LDA*c]=SUB[r2+(size_t)LDV*c]; }
  __syncthreads();
  for(int i=m-1;i>=0;--i){
    if(sh->tq[i]!=0.0) app_left(MU, LDA, i, m, 0, m, TB+(size_t)LDV*i, sh->tq[i], tid);
    __syncthreads();
  }
  for(int w=tid;w<m*m;w+=NT){ int c=w/m, r2=w-c*m; VT2[r2+(size_t)LDV*c]=SVTB[r2+(size_t)LDV*c]; }
  __syncthreads();
  for(int i=m-2;i>=0;--i){
    if(sh->tp[i]!=0.0) app_right(VT2, LDV, 0, m, i+1, m, TB+i, LDV, sh->tp[i], tid);
    __syncthreads();
  }
  for(int w=tid;w<m*NSV;w+=NT){
    int c=w/m, r2=w-c*m;
    rl acc=0.0;
    for(int t=0;t<m;++t) acc += VT2[r2+(size_t)LDV*t]*MQ[t+(size_t)LDA*c];
    MVT[r2+(size_t)LDV*c]=acc;
  }
  __syncthreads();
}

// ---- main kernel ----
__global__ __launch_bounds__(NT)
void mps_kernel(const float* __restrict__ ch, const float* __restrict__ ci,
                const float* __restrict__ ictx, const int* __restrict__ tok)
{
  __shared__ Sh sh;
  int tid = threadIdx.x;
  rl* MA = g_ws + O_MA; rl* MU = g_ws + O_MU; rl* MVT = g_ws + O_MVT;
  int kprev = 0;
  for(int s=0;s<9;++s){
    if(tid==0){
      rl W00=ch[s*4+0], W01=ch[s*4+1], W10=ch[s*4+2], W11=ch[s*4+3];
      rl P00=1,P01=0,P10=0,P11=1;
      for(int mexp=0;mexp<=70;++mexp){
        int j=70-mexp;
        rl v0,v1;
        if(j==0){ v0=ictx[s*2+0]; v1=ictx[s*2+1]; }
        else{
          int b=(tok[j-1]>>(15-s))&1;
          v0=ci[s*4+b]; v1=ci[s*4+2+b];
        }
        g_ws[O_COLS + 0 + 2*j] = P00*v0+P01*v1;
        g_ws[O_COLS + 1 + 2*j] = P10*v0+P11*v1;
        rl n00=W00*P00+W01*P10, n01=W00*P01+W01*P11;
        rl n10=W10*P00+W11*P10, n11=W10*P01+W11*P11;
        P00=n00;P01=n01;P10=n10;P11=n11;
      }
    }
    __syncthreads();
    int m = (s==0)?2:2*kprev;
    for(int w=tid; w<m*NSV; w+=NT){
      int j=w/m, r2=w-j*m;
      int l=r2>>1, dd2=r2&1;
      rl cv = g_ws[O_COLS + dd2 + 2*j];
      MA[r2+(size_t)LDA*j] = (s==0)? cv : g_ws[O_CAR + l + 64*j]*cv;
    }
    __syncthreads();
    if(m==128) svd_tall(&sh, tid);
    else if(m==64) svd_mid(&sh, tid);
    else svd_wide(m, &sh, tid);
    int k = min(64, min(m, NSV));
    __syncthreads();
    for(int w=tid; w<k*NSV; w+=NT){
      int j=w/k, l=w-j*k;
      g_ws[O_CAR + l + 64*j] = sh.d[l]*MVT[l+(size_t)LDV*j];
    }
    __syncthreads();
    if(s==8){
      if(tid==0){
        rl W00=ch[8*4+0], W01=ch[8*4+1], W10=ch[8*4+2], W11=ch[8*4+3];
        rl P00=1,P01=0,P10=0,P11=1;
        for(int it=0;it<30;++it){
          rl n00=W00*P00+W01*P10, n01=W00*P01+W01*P11;
          rl n10=W10*P00+W11*P10, n11=W10*P01+W11*P11;
          P00=n00;P01=n01;P10=n10;P11=n11;
        }
        sh.sc[0]=P00+P10; sh.sc[1]=P01+P11;
      }
      __syncthreads();
      for(int r2=tid; r2<64; r2+=NT){
        rl acc=0.0;
        for(int l=0;l<64;++l)
          acc += sh.sc[0]*MU[(2*l)+(size_t)LDA*r2] + sh.sc[1]*MU[(2*l+1)+(size_t)LDA*r2];
        g_ws[O_VEC + r2] = acc/188.0;
      }
    }
    kprev = k;
    __syncthreads();
  }
}

__global__ __launch_bounds__(NT)
void head_kernel(const float* __restrict__ hw, const float* __restrict__ hb,
                 float* __restrict__ out)
{
  __shared__ float v[64];
  int tid=threadIdx.x;
  if(tid<64) v[tid]=(float)g_ws[O_VEC + tid];
  __syncthreads();
  int i = blockIdx.x*NT + tid;
  if(i<VOCAB){
    const float4* row = (const float4*)(hw + (size_t)i*64);
    float acc=0.f;
    #pragma unroll
    for(int c4=0;c4<16;++c4){
      float4 r4=row[c4];
      acc += r4.x*v[4*c4] + r4.y*v[4*c4+1] + r4.z*v[4*c4+2] + r4.w*v[4*c4+3];
    }
    out[i]=acc+hb[i];
  }
}

extern "C" void kernel_launch(void* const* d_in, const int* in_sizes, int n_in,
                              void* d_out, int out_size, void* d_ws, size_t ws_size,
                              hipStream_t stream)
{
  const float* ch  = (const float*)d_in[0];
  const float* ci  = (const float*)d_in[1];
  const float* hw  = (const float*)d_in[2];
  const float* hb  = (const float*)d_in[3];
  const float* ict = (const float*)d_in[4];
  const int*   tk  = (const int*)d_in[5];
  (void)d_ws; (void)ws_size; (void)in_sizes; (void)n_in; (void)out_size;

  hipLaunchKernelGGL(mps_kernel, dim3(1), dim3(NT), 0, stream, ch, ci, ict, tk);
  hipLaunchKernelGGL(head_kernel, dim3((VOCAB+NT-1)/NT), dim3(NT), 0, stream,
                     hw, hb, (float*)d_out);
}

// Round 4
// 22903.920 us; speedup vs baseline: 2.3339x; 2.3339x over previous
//
#include <hip/hip_runtime.h>

typedef double rl;
#define NT 256
#define NSV 71
#define LDA 128
#define LDV 72
#define SML 25
#define VOCAB 128000
#define LP 27   // LDS leaf pitch

// fp32 LAPACK constants (reference is numpy sgesdd in float32)
#define EPS32 1.1920928955078125e-7
#define UNFL32 1.17549435e-38

// g_ws offsets (doubles)
#define O_CAR   0
#define O_COLS  4608
#define O_VEC   4800
#define O_MA    5120
#define O_MB    14336
#define O_MU    23552
#define O_MQ    32768
#define O_MVT   41984
#define O_SUB   47168
#define O_SVTB  52352
#define O_U2    57536
#define O_VT2   62720
#define O_QU    67904
#define O_QV    73088
#define O_TB    78272

__device__ double g_ws[84000];

struct Sh {
  rl d[72], e[72], tq[72], tp[72], rc[72], rs[72];
  rl dsig[72], zz[72], zh[72], sigm[72], vals[72];
  rl ta[72], tb[72];
  rl b1[72], b2[72], b3[72], b4[72];
  rl LVT[26*LP], LU[26*LP];
  int srcU[72], srcVT[72], perm[72];
  int ia[72], ib[72], ic[72];
  int opk[12], opf[12], opa[12], opb[12], opq[12];
  rl sc[8];
  int si[16];
};

__device__ __forceinline__ rl d_sign(rl a, rl b){ return (b >= 0.0) ? fabs(a) : -fabs(a); }
__device__ __forceinline__ rl dlapy2(rl x, rl y){
  rl ax=fabs(x), ay=fabs(y);
  rl w = ax>ay?ax:ay, z = ax>ay?ay:ax;
  if(z==0.0) return w;
  rl t = z/w; return w*sqrt(1.0+t*t);
}
// LAPACK >= 3.10 dlartg convention (modern OpenBLAS)
__device__ void dlartg(rl f, rl g, rl* cs, rl* sn, rl* r){
  if(g==0.0){ *cs=1.0; *sn=0.0; *r=f; }
  else if(f==0.0){ *cs=0.0; *sn=d_sign(1.0,g); *r=fabs(g); }
  else{
    rl dd = sqrt(f*f+g*g);
    *cs = fabs(f)/dd;
    *r  = d_sign(dd, f);
    *sn = g/(*r);
  }
}

__device__ void dlas2(rl f, rl g, rl h, rl* ssmin, rl* ssmax){
  rl fa=fabs(f), ga=fabs(g), ha=fabs(h);
  rl fhmn=fmin(fa,ha), fhmx=fmax(fa,ha);
  if(fhmn==0.0){
    *ssmin=0.0;
    if(fhmx==0.0) *ssmax=ga;
    else { rl mx=fmax(fhmx,ga), mn=fmin(fhmx,ga); rl q=mn/mx; *ssmax=mx*sqrt(1.0+q*q); }
  } else {
    if(ga < fhmx){
      rl as=1.0+fhmn/fhmx, at=(fhmx-fhmn)/fhmx;
      rl au=(ga/fhmx); au=au*au;
      rl c=2.0/(sqrt(as*as+au)+sqrt(at*at+au));
      *ssmin=fhmn*c; *ssmax=fhmx/c;
    } else {
      rl au=fhmx/ga;
      if(au==0.0){ *ssmin=(fhmn*fhmx)/ga; *ssmax=ga; }
      else{
        rl as=1.0+fhmn/fhmx, at=(fhmx-fhmn)/fhmx;
        rl c=1.0/(sqrt(1.0+(as*au)*(as*au))+sqrt(1.0+(at*au)*(at*au)));
        *ssmin=(fhmn*c)*au; *ssmin=*ssmin+*ssmin;
        *ssmax=ga/(c+c);
      }
    }
  }
}

__device__ void dlasv2(rl f, rl g, rl h, rl* ssmin, rl* ssmax, rl* snr, rl* csr, rl* snl, rl* csl){
  rl ft=f, fa=fabs(f), ht=h, ha=fabs(h);
  int pmax=1;
  bool swp = (ha > fa);
  if(swp){ pmax=3; rl t=ft; ft=ht; ht=t; t=fa; fa=ha; ha=t; }
  rl gt=g, ga=fabs(g);
  rl clt=0, crt=0, slt=0, srt=0;
  if(ga==0.0){ *ssmin=ha; *ssmax=fa; clt=1.0; crt=1.0; slt=0.0; srt=0.0; }
  else{
    bool gasmal=true;
    if(ga > fa){
      pmax=2;
      if((fa/ga) < EPS32){
        gasmal=false;
        *ssmax=ga;
        if(ha>1.0) *ssmin=fa/(ga/ha); else *ssmin=(fa/ga)*ha;
        clt=1.0; slt=ht/gt; srt=1.0; crt=ft/gt;
      }
    }
    if(gasmal){
      rl dd=fa-ha;
      rl lv = (dd==fa) ? 1.0 : dd/fa;
      rl mq = gt/ft;
      rl tv = 2.0-lv;
      rl mm = mq*mq, tt = tv*tv;
      rl sv = sqrt(tt+mm);
      rl rv = (lv==0.0) ? fabs(mq) : sqrt(lv*lv+mm);
      rl a = 0.5*(sv+rv);
      *ssmin = ha/a; *ssmax = fa*a;
      rl t3;
      if(mm==0.0){
        if(lv==0.0) t3 = d_sign(2.0, ft)*d_sign(1.0, gt);
        else t3 = gt/d_sign(dd, ft) + mq/tv;
      } else {
        t3 = (mq/(sv+tv) + mq/(rv+lv))*(1.0+a);
      }
      rl l2 = sqrt(t3*t3+4.0);
      crt = 2.0/l2; srt = t3/l2;
      clt = (crt + srt*mq)/a;
      slt = (ht/ft)*srt/a;
    }
  }
  if(swp){ *csl=srt; *snl=crt; *csr=slt; *snr=clt; }
  else  { *csl=clt; *snl=slt; *csr=crt; *snr=srt; }
  rl tsign=1.0;
  if(pmax==1) tsign = d_sign(1.0,*csr)*d_sign(1.0,*csl)*d_sign(1.0,f);
  if(pmax==2) tsign = d_sign(1.0,*snr)*d_sign(1.0,*csl)*d_sign(1.0,g);
  if(pmax==3) tsign = d_sign(1.0,*snr)*d_sign(1.0,*snl)*d_sign(1.0,h);
  *ssmax = d_sign(*ssmax, tsign);
  *ssmin = d_sign(*ssmin, tsign*d_sign(1.0,f)*d_sign(1.0,h));
}

__device__ void app_left(rl* A, int ld, int r0, int m, int c0, int n, const rl* vbase, rl tau, int tid){
  for(int c=c0+tid; c<n; c+=NT){
    rl* col = A + (size_t)ld*c;
    rl w = col[r0];
    for(int r=r0+1;r<m;++r) w += col[r]*vbase[r];
    w *= tau;
    col[r0] -= w;
    for(int r=r0+1;r<m;++r) col[r] -= w*vbase[r];
  }
}
__device__ void app_right(rl* A, int ld, int r0, int m, int c0, int n, const rl* vbase, int vstride, rl tau, int tid){
  for(int r=r0+tid; r<m; r+=NT){
    rl w = A[r + (size_t)ld*c0];
    for(int c=c0+1;c<n;++c) w += A[r + (size_t)ld*c]*vbase[(size_t)vstride*c];
    w *= tau;
    A[r + (size_t)ld*c0] -= w;
    for(int c=c0+1;c<n;++c) A[r + (size_t)ld*c] -= w*vbase[(size_t)vstride*c];
  }
}

// ---- cooperative dbdsqr on LDS leaf blocks ----
// VT = sh->LVT (row r, col c at LVT[r*LP+c]), ncvt cols; U = sh->LU (row r, col j), nru rows.
// tid0 runs the scalar d/e control; rotation batches applied in parallel.
__device__ void bdsqr_coop(int n, rl* d, rl* e, int ncvt, int nru, Sh* sh, int tid){
  if(n>1){
    rl eps=EPS32, unfl=UNFL32;
    rl tolmul=fmax(10.0,fmin(100.0,pow(eps,-0.125)));
    rl tol=tolmul*eps;
    rl thresh=0.0;
    int mm=n-1, oldll=-2, oldm=-2, idir=0, iter=0, maxit=6*n*n;
    if(tid==0){
      rl sminoa=fabs(d[0]);
      if(sminoa!=0.0){
        rl mu=sminoa;
        for(int i=1;i<n;++i){ mu=fabs(d[i])*(mu/(mu+fabs(e[i-1]))); sminoa=fmin(sminoa,mu); if(sminoa==0.0)break; }
      }
      sminoa=sminoa/sqrt((rl)n);
      thresh=fmax(tol*sminoa,(rl)(6*n*n)*unfl);
    }
    while(true){
      if(tid==0){
        int act=0, p_lo=0, p_cnt=0, p_fwd=1, p_mm=0;
        while(mm>0){
          if(iter>maxit) break;
          rl smax=fabs(d[mm]), smin=smax;
          int ll=-1;
          for(int lll=mm-1;lll>=0;--lll){
            rl abss=fabs(d[lll]), abse=fabs(e[lll]);
            if(abse<=thresh){ ll=lll; break; }
            smin=fmin(smin,abss);
            smax=fmax(smax,fmax(abss,abse));
          }
          if(ll==mm-1){ e[ll]=0.0; mm=mm-1; continue; }
          if(ll>=0) e[ll]=0.0;
          int lo=ll+1;
          if(mm==lo+1){
            rl sigmn,sigmx,sinr,cosr,sinl,cosl;
            dlasv2(d[lo],e[lo],d[mm],&sigmn,&sigmx,&sinr,&cosr,&sinl,&cosl);
            d[lo]=sigmx; d[mm]=sigmn; e[lo]=0.0;
            sh->sc[0]=cosr; sh->sc[1]=sinr; sh->sc[2]=cosl; sh->sc[3]=sinl;
            act=2; p_lo=lo; p_mm=mm;
            mm-=2;
            break;
          }
          if(lo>oldm || mm<oldll) idir=(fabs(d[lo])>=fabs(d[mm]))?1:2;
          rl sminl=0.0; int conv=0;
          if(idir==1){
            if(fabs(e[mm-1])<=tol*fabs(d[mm])){ e[mm-1]=0.0; conv=1; }
            if(!conv){
              rl mu=fabs(d[lo]); sminl=mu;
              for(int lll=lo;lll<mm;++lll){
                if(fabs(e[lll])<=tol*mu){ e[lll]=0.0; conv=1; break; }
                mu=fabs(d[lll+1])*(mu/(mu+fabs(e[lll])));
                sminl=fmin(sminl,mu);
              }
            }
          } else {
            if(fabs(e[lo])<=tol*fabs(d[lo])){ e[lo]=0.0; conv=1; }
            if(!conv){
              rl mu=fabs(d[mm]); sminl=mu;
              for(int lll=mm-1;lll>=lo;--lll){
                if(fabs(e[lll])<=tol*mu){ e[lll]=0.0; conv=1; break; }
                mu=fabs(d[lll])*(mu/(mu+fabs(e[lll])));
                sminl=fmin(sminl,mu);
              }
            }
          }
          if(conv) continue;
          oldll=lo; oldm=mm;
          rl shift=0.0, rr_;
          if(!((rl)n*tol*(sminl/smax) <= fmax(eps, 0.01*tol))){
            rl sll;
            if(idir==1){ sll=fabs(d[lo]); dlas2(d[mm-1],e[mm-1],d[mm],&shift,&rr_); }
            else { sll=fabs(d[mm]); dlas2(d[lo],e[lo],d[lo+1],&shift,&rr_); }
            if(sll>0.0){ rl q=shift/sll; if(q*q<eps) shift=0.0; }
          }
          iter += mm-lo;
          int cnt=mm-lo;
          if(shift==0.0){
            if(idir==1){
              rl cs=1.0, oldcs=1.0, sn=0.0, oldsn=0.0, r;
              for(int i=lo;i<mm;++i){
                dlartg(d[i]*cs,e[i],&cs,&sn,&r);
                if(i>lo) e[i-1]=oldsn*r;
                dlartg(oldcs*r, d[i+1]*sn, &oldcs,&oldsn,&d[i]);
                sh->b1[i-lo]=cs; sh->b2[i-lo]=sn; sh->b3[i-lo]=oldcs; sh->b4[i-lo]=oldsn;
              }
              rl h=d[mm]*cs; d[mm]=h*oldcs; e[mm-1]=h*oldsn;
              p_fwd=1;
              if(fabs(e[mm-1])<=thresh) e[mm-1]=0.0;
            } else {
              rl cs=1.0, oldcs=1.0, sn=0.0, oldsn=0.0, r;
              for(int i=mm;i>lo;--i){
                dlartg(d[i]*cs,e[i-1],&cs,&sn,&r);
                if(i<mm) e[i]=oldsn*r;
                dlartg(oldcs*r,d[i-1]*sn,&oldcs,&oldsn,&d[i]);
                int j=i-lo-1;
                sh->b1[j]=oldcs; sh->b2[j]=-oldsn; sh->b3[j]=cs; sh->b4[j]=-sn;
              }
              rl h=d[lo]*cs; d[lo]=h*oldcs; e[lo]=h*oldsn;
              p_fwd=0;
              if(fabs(e[lo])<=thresh) e[lo]=0.0;
            }
          } else {
            if(idir==1){
              rl f2=(fabs(d[lo])-shift)*(d_sign(1.0,d[lo])+shift/d[lo]);
              rl g2=e[lo], r, cosr,sinr,cosl,sinl;
              for(int i=lo;i<mm;++i){
                dlartg(f2,g2,&cosr,&sinr,&r);
                if(i>lo) e[i-1]=r;
                f2=cosr*d[i]+sinr*e[i];
                e[i]=cosr*e[i]-sinr*d[i];
                g2=sinr*d[i+1];
                d[i+1]=cosr*d[i+1];
                dlartg(f2,g2,&cosl,&sinl,&r);
                d[i]=r;
                f2=cosl*e[i]+sinl*d[i+1];
                d[i+1]=cosl*d[i+1]-sinl*e[i];
                if(i<mm-1){ g2=sinl*e[i+1]; e[i+1]=cosl*e[i+1]; }
                sh->b1[i-lo]=cosr; sh->b2[i-lo]=sinr; sh->b3[i-lo]=cosl; sh->b4[i-lo]=sinl;
              }
              e[mm-1]=f2;
              p_fwd=1;
              if(fabs(e[mm-1])<=thresh) e[mm-1]=0.0;
            } else {
              rl f2=(fabs(d[mm])-shift)*(d_sign(1.0,d[mm])+shift/d[mm]);
              rl g2=e[mm-1], r, cosr,sinr,cosl,sinl;
              for(int i=mm;i>lo;--i){
                dlartg(f2,g2,&cosr,&sinr,&r);
                if(i<mm) e[i]=r;
                f2=cosr*d[i]+sinr*e[i-1];
                e[i-1]=cosr*e[i-1]-sinr*d[i];
                g2=sinr*d[i-1];
                d[i-1]=cosr*d[i-1];
                dlartg(f2,g2,&cosl,&sinl,&r);
                d[i]=r;
                f2=cosl*e[i-1]+sinl*d[i-1];
                d[i-1]=cosl*d[i-1]-sinl*e[i-1];
                if(i>lo+1){ g2=sinl*e[i-2]; e[i-2]=cosl*e[i-2]; }
                int j=i-lo-1;
                sh->b1[j]=cosl; sh->b2[j]=-sinl; sh->b3[j]=cosr; sh->b4[j]=-sinr;
              }
              e[lo]=f2;
              p_fwd=0;
              if(fabs(e[lo])<=thresh) e[lo]=0.0;
            }
          }
          act=1; p_lo=lo; p_cnt=cnt;
          break;
        }
        sh->si[7]=act; sh->si[8]=p_lo; sh->si[9]=p_cnt; sh->si[10]=p_fwd; sh->si[11]=p_mm;
      }
      __syncthreads();
      int act=sh->si[7];
      if(act==0) break;
      if(act==1){
        int lo=sh->si[8], cnt=sh->si[9], fwd=sh->si[10];
        if(tid<ncvt){
          int k=tid;
          if(fwd){
            for(int j=0;j<cnt;++j){
              rl c=sh->b1[j], s=sh->b2[j];
              rl t=sh->LVT[(lo+j+1)*LP+k];
              sh->LVT[(lo+j+1)*LP+k]=c*t-s*sh->LVT[(lo+j)*LP+k];
              sh->LVT[(lo+j)*LP+k]=s*t+c*sh->LVT[(lo+j)*LP+k];
            }
          } else {
            for(int j=cnt-1;j>=0;--j){
              rl c=sh->b1[j], s=sh->b2[j];
              rl t=sh->LVT[(lo+j+1)*LP+k];
              sh->LVT[(lo+j+1)*LP+k]=c*t-s*sh->LVT[(lo+j)*LP+k];
              sh->LVT[(lo+j)*LP+k]=s*t+c*sh->LVT[(lo+j)*LP+k];
            }
          }
        } else if(tid<ncvt+nru){
          int r2=tid-ncvt;
          if(fwd){
            for(int j=0;j<cnt;++j){
              rl c=sh->b3[j], s=sh->b4[j];
              rl t=sh->LU[r2*LP+(lo+j+1)];
              sh->LU[r2*LP+(lo+j+1)]=c*t-s*sh->LU[r2*LP+(lo+j)];
              sh->LU[r2*LP+(lo+j)]=s*t+c*sh->LU[r2*LP+(lo+j)];
            }
          } else {
            for(int j=cnt-1;j>=0;--j){
              rl c=sh->b3[j], s=sh->b4[j];
              rl t=sh->LU[r2*LP+(lo+j+1)];
              sh->LU[r2*LP+(lo+j+1)]=c*t-s*sh->LU[r2*LP+(lo+j)];
              sh->LU[r2*LP+(lo+j)]=s*t+c*sh->LU[r2*LP+(lo+j)];
            }
          }
        }
      } else {
        int lo=sh->si[8], m2=sh->si[11];
        rl cosr=sh->sc[0], sinr=sh->sc[1], cosl=sh->sc[2], sinl=sh->sc[3];
        if(tid<ncvt){
          rl x=sh->LVT[lo*LP+tid], y=sh->LVT[m2*LP+tid];
          sh->LVT[lo*LP+tid]=cosr*x+sinr*y; sh->LVT[m2*LP+tid]=cosr*y-sinr*x;
        } else if(tid<ncvt+nru){
          int r2=tid-ncvt;
          rl x=sh->LU[r2*LP+lo], y=sh->LU[r2*LP+m2];
          sh->LU[r2*LP+lo]=cosl*x+sinl*y; sh->LU[r2*LP+m2]=cosl*y-sinl*x;
        }
      }
      __syncthreads();
    }
  }
  // sign flips + descending sort (decisions tid0; application parallel)
  if(tid==0){
    for(int i=0;i<n;++i){ sh->ic[i]=(d[i]<0.0)?1:0; if(d[i]<0.0) d[i]=-d[i]; }
    int nsw=0;
    for(int i=0;i<n-1;++i){
      int isub=0; rl smin=d[0];
      for(int j=1;j<n-i;++j){ if(d[j]<=smin){ isub=j; smin=d[j]; } }
      int tgt=n-1-i;
      if(isub!=tgt){
        d[isub]=d[tgt]; d[tgt]=smin;
        sh->ia[nsw]=isub; sh->ib[nsw]=tgt; ++nsw;
      }
    }
    sh->si[7]=nsw;
  }
  __syncthreads();
  int nsw=sh->si[7];
  if(tid<ncvt){
    for(int i=0;i<n;++i) if(sh->ic[i]) sh->LVT[i*LP+tid]=-sh->LVT[i*LP+tid];
    for(int w2=0;w2<nsw;++w2){
      int a=sh->ia[w2], b=sh->ib[w2];
      rl t=sh->LVT[a*LP+tid]; sh->LVT[a*LP+tid]=sh->LVT[b*LP+tid]; sh->LVT[b*LP+tid]=t;
    }
  } else if(tid<ncvt+nru){
    int r2=tid-ncvt;
    for(int w2=0;w2<nsw;++w2){
      int a=sh->ia[w2], b=sh->ib[w2];
      rl t=sh->LU[r2*LP+a]; sh->LU[r2*LP+a]=sh->LU[r2*LP+b]; sh->LU[r2*LP+b]=t;
    }
  }
  __syncthreads();
}

// ---- leaf: dlasdq on LDS copies of the diagonal blocks ----
__device__ void leaf_exec(int f, int n, int sqre, int wantU, Sh* sh, int tid){
  rl* SVTB = g_ws + O_SVTB; rl* SUB = g_ws + O_SUB;
  int np = n + sqre;
  for(int w=tid; w<np*np; w+=NT){ int r2=w/np, c=w-r2*np; sh->LVT[r2*LP+c]=SVTB[(f+r2)+(size_t)LDV*(f+c)]; }
  if(wantU) for(int w=tid; w<n*n; w+=NT){ int r2=w/n, c=w-r2*n; sh->LU[r2*LP+c]=SUB[(f+r2)+(size_t)LDV*(f+c)]; }
  __syncthreads();
  if(sqre==1){
    if(tid==0){
      rl cs,snv,rv; rl* dd=sh->d+f; rl* ee=sh->e+f;
      for(int i=0;i<n;++i){
        dlartg(dd[i],ee[i],&cs,&snv,&rv);
        dd[i]=rv;
        if(i<n-1){ ee[i]=snv*dd[i+1]; dd[i+1]=cs*dd[i+1]; }
        else ee[i]=0.0;
        sh->b1[i]=cs; sh->b2[i]=snv;
      }
    }
    __syncthreads();
    if(tid<np){
      for(int j=0;j<n;++j){
        rl cj=sh->b1[j], sj=sh->b2[j];
        rl t=sh->LVT[(j+1)*LP+tid];
        sh->LVT[(j+1)*LP+tid]=cj*t-sj*sh->LVT[j*LP+tid];
        sh->LVT[j*LP+tid]=sj*t+cj*sh->LVT[j*LP+tid];
      }
    }
    __syncthreads();
    if(tid==0){
      rl cs,snv,rv; rl* dd=sh->d+f; rl* ee=sh->e+f;
      for(int i=0;i<n-1;++i){
        dlartg(dd[i],ee[i],&cs,&snv,&rv);
        dd[i]=rv; ee[i]=snv*dd[i+1]; dd[i+1]=cs*dd[i+1];
        sh->b1[i]=cs; sh->b2[i]=snv;
      }
    }
    __syncthreads();
    if(wantU && tid<n){
      for(int j=0;j<n-1;++j){
        rl cj=sh->b1[j], sj=sh->b2[j];
        rl t=sh->LU[tid*LP+(j+1)];
        sh->LU[tid*LP+(j+1)]=cj*t-sj*sh->LU[tid*LP+j];
        sh->LU[tid*LP+j]=sj*t+cj*sh->LU[tid*LP+j];
      }
    }
    __syncthreads();
  }
  bdsqr_coop(n, sh->d+f, sh->e+f, np, wantU? n:0, sh, tid);
  for(int w=tid; w<np*np; w+=NT){ int r2=w/np, c=w-r2*np; SVTB[(f+r2)+(size_t)LDV*(f+c)]=sh->LVT[r2*LP+c]; }
  if(wantU) for(int w=tid; w<n*n; w+=NT){ int r2=w/n, c=w-r2*n; SUB[(f+r2)+(size_t)LDV*(f+c)]=sh->LU[r2*LP+c]; }
  __syncthreads();
}

// ---- D&C merge (dlasd1/2/3) ----
__device__ void lasd1_merge(int f, int nl, int nr, int sqre, int wantU, Sh* sh, int tid){
  rl* SUB = g_ws + O_SUB; rl* SVTB = g_ws + O_SVTB;
  rl* U2 = g_ws + O_U2; rl* VT2 = g_ws + O_VT2; rl* QU = g_ws + O_QU; rl* QV = g_ws + O_QV;
  int n = nl+nr+1, m = n+sqre;
  if(tid==0){
    rl alpha = sh->d[f+nl], beta = sh->e[f+nl];
    sh->vals[0]=0.0;
    sh->zz[0] = alpha*SVTB[(f+nl)+(size_t)LDV*(f+nl)];
    sh->srcU[0]=-1; sh->srcVT[0]=f+nl;
    for(int i=0;i<nl;++i){
      sh->vals[1+i]=sh->d[f+i];
      sh->zz[1+i]=alpha*SVTB[(f+i)+(size_t)LDV*(f+nl)];
      sh->srcU[1+i]=f+i; sh->srcVT[1+i]=f+i;
    }
    for(int j=0;j<nr;++j){
      sh->vals[1+nl+j]=sh->d[f+nl+1+j];
      sh->zz[1+nl+j]=beta*SVTB[(f+nl+1+j)+(size_t)LDV*(f+nl+1)];
      sh->srcU[1+nl+j]=f+nl+1+j; sh->srcVT[1+nl+j]=f+nl+1+j;
    }
    sh->sc[0]=alpha; sh->sc[1]=beta;
    if(sqre==1){
      rl zM = beta*SVTB[(f+n)+(size_t)LDV*(f+nl+1)];
      rl c,s,r2;
      dlartg(sh->zz[0], zM, &c, &s, &r2);
      sh->zz[0]=r2; sh->sc[2]=c; sh->sc[3]=s;
    }
  }
  __syncthreads();
  if(sqre==1){
    rl c=sh->sc[2], s=sh->sc[3];
    int ra=f+nl, rb=f+n;
    for(int k=tid;k<m;k+=NT){
      size_t ci=(size_t)LDV*(f+k);
      rl a=SVTB[ra+ci], b=SVTB[rb+ci];
      SVTB[ra+ci]=c*a+s*b; SVTB[rb+ci]=-s*a+c*b;
    }
  }
  __syncthreads();
  if(tid==0){
    rl maxd=0.0; for(int i=0;i<n;++i) maxd=fmax(maxd,fabs(sh->vals[i]));
    rl tol = 8.0*EPS32*fmax(maxd, fmax(fabs(sh->sc[0]), fabs(sh->sc[1])));
    int nds=0;
    sh->ic[nds++]=0;
    for(int i=1;i<n;++i) if(fabs(sh->zz[i]) > tol) sh->ic[nds++]=i;
    for(int a=1;a<nds;++a){
      int key=sh->ic[a]; rl kv=sh->vals[key]; int b=a-1;
      while(b>=1 && sh->vals[sh->ic[b]] > kv){ sh->ic[b+1]=sh->ic[b]; --b; }
      sh->ic[b+1]=key;
    }
    int K=nds, pos=nds;
    for(int i=1;i<n;++i) if(fabs(sh->zz[i]) <= tol) sh->ic[pos++]=i;
    for(int a=K+1;a<n;++a){
      int key=sh->ic[a]; rl kv=sh->vals[key]; int b=a-1;
      while(b>=K && sh->vals[sh->ic[b]] > kv){ sh->ic[b+1]=sh->ic[b]; --b; }
      sh->ic[b+1]=key;
    }
    for(int t=0;t<n;++t){ sh->ta[t]=sh->vals[t]; sh->tb[t]=sh->zz[t]; sh->ia[t]=sh->srcU[t]; sh->ib[t]=sh->srcVT[t]; }
    for(int t=0;t<n;++t){
      int p=sh->ic[t];
      sh->dsig[t]=sh->ta[p]; sh->zz[t]=sh->tb[p]; sh->srcU[t]=sh->ia[p]; sh->srcVT[t]=sh->ib[p];
    }
    rl rho=0.0; for(int t=0;t<K;++t){ rl zv=sh->zz[t]; rho += zv*zv; }
    sh->sc[4]=rho;
    sh->si[0]=K; sh->si[1]=n; sh->si[2]=m; sh->si[3]=f; sh->si[4]=nl;
  }
  __syncthreads();
  int K=sh->si[0], n_=sh->si[1], m_=sh->si[2], f_=sh->si[3], nl_=sh->si[4];
  if(wantU){
    for(int w=tid; w<n_*n_; w+=NT){
      int col=w/n_, row=w-col*n_;
      int su=sh->srcU[col];
      rl v;
      if(su<0) v = (row==nl_) ? 1.0 : 0.0;
      else v = SUB[(f_+row)+(size_t)LDV*su];
      U2[row+(size_t)LDV*col]=v;
    }
  }
  for(int w=tid; w<n_*m_; w+=NT){
    int row=w/m_, col=w-row*m_;
    VT2[row+(size_t)LDV*col] = SVTB[sh->srcVT[row]+(size_t)LDV*(f_+col)];
  }
  __syncthreads();
  rl rho=sh->sc[4];
  for(int j=tid;j<K;j+=NT){
    rl lo=sh->dsig[j];
    rl hi=(j<K-1)? sh->dsig[j+1] : sqrt(sh->dsig[K-1]*sh->dsig[K-1]+rho);
    for(int it=0; it<130; ++it){
      rl mid=0.5*(lo+hi);
      if(mid<=lo || mid>=hi) break;
      rl g=1.0;
      for(int i2=0;i2<K;++i2){
        rl zi=sh->zz[i2];
        g += zi*zi/((sh->dsig[i2]-mid)*(sh->dsig[i2]+mid));
      }
      if(g<0.0) lo=mid; else hi=mid;
    }
    sh->sigm[j]=0.5*(lo+hi);
  }
  __syncthreads();
  for(int i2=tid;i2<K;i2+=NT){
    rl di=sh->dsig[i2];
    rl p=(di - sh->sigm[K-1])*(di + sh->sigm[K-1]);
    for(int j=0;j<i2;++j)
      p *= (di - sh->sigm[j])*(di + sh->sigm[j])/((di - sh->dsig[j])*(di + sh->dsig[j]));
    for(int j=i2;j<K-1;++j)
      p *= (di - sh->sigm[j])*(di + sh->sigm[j])/((di - sh->dsig[j+1])*(di + sh->dsig[j+1]));
    sh->zh[i2] = d_sign(sqrt(fabs(p)), sh->zz[i2]);
  }
  __syncthreads();
  for(int j=tid;j<K;j+=NT){
    rl sj=sh->sigm[j];
    rl nu=0.0, nv=0.0;
    for(int i2=0;i2<K;++i2){
      rl di=sh->dsig[i2];
      rl vv=sh->zh[i2]/((di-sj)*(di+sj));
      QV[i2+(size_t)LDV*j]=vv; nv+=vv*vv;
      if(wantU){
        rl uu=(i2==0)? -1.0 : di*vv;
        QU[i2+(size_t)LDV*j]=uu; nu+=uu*uu;
      }
    }
    nv=1.0/sqrt(nv);
    for(int i2=0;i2<K;++i2) QV[i2+(size_t)LDV*j]*=nv;
    if(wantU){
      nu=1.0/sqrt(nu);
      for(int i2=0;i2<K;++i2) QU[i2+(size_t)LDV*j]*=nu;
    }
  }
  __syncthreads();
  if(tid==0){
    int nd2=n_-K;
    for(int t=0;t<nd2;++t) sh->ia[t]=K+t;
    int ps=K-1, pd=nd2-1;
    int t=0;
    while(t<n_){
      rl vs = (ps>=0)? sh->sigm[ps] : -1.0;
      rl vd = (pd>=0)? sh->dsig[sh->ia[pd]] : -1.0;
      if(vs >= vd){ sh->perm[t]=ps; sh->vals[t]=vs; --ps; }
      else { sh->perm[t]=1000+sh->ia[pd]; sh->vals[t]=vd; --pd; }
      ++t;
    }
    for(int q=0;q<n_;++q) sh->d[f_+q]=sh->vals[q];
  }
  __syncthreads();
  if(wantU){
    for(int w=tid; w<n_*n_; w+=NT){
      int t=w/n_, row=w-t*n_;
      int src=sh->perm[t];
      rl acc;
      if(src>=1000) acc = U2[row+(size_t)LDV*(src-1000)];
      else{
        acc=0.0;
        for(int i2=0;i2<K;++i2) acc += U2[row+(size_t)LDV*i2]*QU[i2+(size_t)LDV*src];
      }
      SUB[(f_+row)+(size_t)LDV*(f_+t)] = acc;
    }
  }
  for(int w=tid; w<n_*m_; w+=NT){
    int t=w/m_, col=w-t*m_;
    int src=sh->perm[t];
    rl acc;
    if(src>=1000) acc = VT2[(src-1000)+(size_t)LDV*col];
    else{
      acc=0.0;
      for(int i2=0;i2<K;++i2) acc += QV[i2+(size_t)LDV*src]*VT2[i2+(size_t)LDV*col];
    }
    SVTB[(f_+t)+(size_t)LDV*(f_+col)] = acc;
  }
  __syncthreads();
}

// ---- dlasd0: iterative post-order over the D&C tree ----
__device__ void run_dc(int n, int wantU, Sh* sh, int tid){
  if(tid==0){
    int sf[12], sn2[12], sq[12], sv[12]; int sp=0, no=0;
    sf[0]=0; sn2[0]=n; sq[0]=0; sv[0]=0; sp=1;
    while(sp>0){
      --sp;
      int f=sf[sp], nn=sn2[sp], q=sq[sp], v=sv[sp];
      if(nn<=SML){ sh->opk[no]=0; sh->opf[no]=f; sh->opa[no]=nn; sh->opq[no]=q; ++no; }
      else if(v==0){
        int nl=nn/2, nr=nn-nl-1;
        sf[sp]=f; sn2[sp]=nn; sq[sp]=q; sv[sp]=1; ++sp;
        sf[sp]=f+nl+1; sn2[sp]=nr; sq[sp]=q; sv[sp]=0; ++sp;
        sf[sp]=f; sn2[sp]=nl; sq[sp]=1; sv[sp]=0; ++sp;
      } else {
        int nl=nn/2, nr=nn-nl-1;
        sh->opk[no]=1; sh->opf[no]=f; sh->opa[no]=nl; sh->opb[no]=nr; sh->opq[no]=q; ++no;
      }
    }
    sh->si[6]=no;
  }
  __syncthreads();
  int no=sh->si[6];
  for(int o=0;o<no;++o){
    if(sh->opk[o]==0) leaf_exec(sh->opf[o], sh->opa[o], sh->opq[o], wantU, sh, tid);
    else lasd1_merge(sh->opf[o], sh->opa[o], sh->opb[o], sh->opq[o], wantU, sh, tid);
  }
}

__device__ void dbdsdc_U(int n, int wantU, Sh* sh, int tid){
  rl* SUB = g_ws + O_SUB; rl* SVTB = g_ws + O_SVTB;
  for(int w=tid; w<LDV*LDV; w+=NT){
    int c=w/LDV, r2=w-c*LDV; rl v=(r2==c)?1.0:0.0;
    SVTB[w]=v;
    if(wantU) SUB[w]=v;
  }
  __syncthreads();
  if(n <= SML) leaf_exec(0, n, 0, wantU, sh, tid);
  else run_dc(n, wantU, sh, tid);
}

__device__ void dbdsdc_L(int n, int wantU, Sh* sh, int tid){
  if(tid==0){
    for(int i=0;i<n-1;++i){
      rl cs,snv,rv;
      dlartg(sh->d[i], sh->e[i], &cs,&snv,&rv);
      sh->d[i]=rv; sh->e[i]=snv*sh->d[i+1]; sh->d[i+1]=cs*sh->d[i+1];
      sh->rc[i]=cs; sh->rs[i]=snv;
    }
  }
  __syncthreads();
  dbdsdc_U(n, wantU, sh, tid);
  if(wantU){
    rl* SUB = g_ws + O_SUB;
    for(int c=tid;c<n;c+=NT){
      size_t ci=(size_t)LDV*c;
      for(int k=n-2;k>=0;--k){
        rl a=SUB[k+ci], b=SUB[k+1+ci];
        SUB[k+ci]  = sh->rc[k]*a - sh->rs[k]*b;
        SUB[k+1+ci]= sh->rs[k]*a + sh->rc[k]*b;
      }
    }
  }
  __syncthreads();
}

// ---- Householder helpers (wave-parallel norm) ----
__device__ void gen_reflect_col(rl* A, int ld, int i, int r0, int m, rl* outBeta, rl* outTau, Sh* sh, int tid){
  if(tid<64){
    rl ps=0.0;
    for(int r=r0+1+tid;r<m;r+=64){ rl v=A[r+(size_t)ld*i]; ps+=v*v; }
    for(int off=32;off>0;off>>=1) ps += __shfl_down(ps,off,64);
    if(tid==0){
      rl alpha=A[r0+(size_t)ld*i];
      rl xn=sqrt(ps);
      rl beta, tau, scl; int doscale;
      if(xn==0.0){ tau=0.0; beta=alpha; scl=0.0; doscale=0; }
      else{ beta=-d_sign(dlapy2(alpha,xn),alpha); tau=(beta-alpha)/beta; scl=1.0/(alpha-beta); doscale=1; }
      sh->sc[5]=beta; sh->sc[6]=tau; sh->sc[7]=scl; sh->si[5]=doscale;
    }
  }
  __syncthreads();
  if(sh->si[5]) for(int r=r0+1+tid;r<m;r+=NT) A[r+(size_t)ld*i]*=sh->sc[7];
  __syncthreads();
  if(tid==0){ *outBeta=sh->sc[5]; *outTau=sh->sc[6]; }
}
__device__ void gen_reflect_row(rl* A, int ld, int i, int c0, int n, rl* outBeta, rl* outTau, Sh* sh, int tid){
  if(tid<64){
    rl ps=0.0;
    for(int c=c0+1+tid;c<n;c+=64){ rl v=A[i+(size_t)ld*c]; ps+=v*v; }
    for(int off=32;off>0;off>>=1) ps += __shfl_down(ps,off,64);
    if(tid==0){
      rl alpha=A[i+(size_t)ld*c0];
      rl xn=sqrt(ps);
      rl beta, tau, scl; int doscale;
      if(xn==0.0){ tau=0.0; beta=alpha; scl=0.0; doscale=0; }
      else{ beta=-d_sign(dlapy2(alpha,xn),alpha); tau=(beta-alpha)/beta; scl=1.0/(alpha-beta); doscale=1; }
      sh->sc[5]=beta; sh->sc[6]=tau; sh->sc[7]=scl; sh->si[5]=doscale;
    }
  }
  __syncthreads();
  if(sh->si[5]) for(int c=c0+1+tid;c<n;c+=NT) A[i+(size_t)ld*c]*=sh->sc[7];
  __syncthreads();
  if(tid==0){ *outBeta=sh->sc[5]; *outTau=sh->sc[6]; }
}

__device__ void gebd2_upper(rl* A, int ld, int m, int n, Sh* sh, int tid){
  for(int i=0;i<n;++i){
    gen_reflect_col(A, ld, i, i, m, &sh->d[i], &sh->tq[i], sh, tid);
    __syncthreads();
    if(sh->tq[i]!=0.0) app_left(A, ld, i, m, i+1, n, A+(size_t)ld*i, sh->tq[i], tid);
    __syncthreads();
    if(i<n-1){
      gen_reflect_row(A, ld, i, i+1, n, &sh->e[i], &sh->tp[i], sh, tid);
      __syncthreads();
      if(sh->tp[i]!=0.0) app_right(A, ld, i+1, m, i+1, n, A+i, ld, sh->tp[i], tid);
      __syncthreads();
    } else { if(tid==0) sh->tp[i]=0.0; __syncthreads(); }
  }
}
__device__ void gebd2_lower(rl* A, int ld, int m, int n, Sh* sh, int tid){
  for(int i=0;i<m;++i){
    gen_reflect_row(A, ld, i, i, n, &sh->d[i], &sh->tp[i], sh, tid);
    __syncthreads();
    if(sh->tp[i]!=0.0) app_right(A, ld, i+1, m, i, n, A+i, ld, sh->tp[i], tid);
    __syncthreads();
    if(i<m-1){
      gen_reflect_col(A, ld, i, i+1, m, &sh->e[i], &sh->tq[i], sh, tid);
      __syncthreads();
      if(sh->tq[i]!=0.0) app_left(A, ld, i+1, m, i+1, n, A+(size_t)ld*i, sh->tq[i], tid);
      __syncthreads();
    }
  }
}
__device__ void gelq2(rl* A, int ld, int m, int n, Sh* sh, int tid){
  for(int i=0;i<m;++i){
    rl beta, tau;
    gen_reflect_row(A, ld, i, i, n, &beta, &tau, sh, tid);
    if(tid==0){ sh->rs[i]=sh->sc[6]; A[i+(size_t)ld*i]=sh->sc[5]; }
    __syncthreads();
    if(i<m-1 && sh->rs[i]!=0.0) app_right(A, ld, i+1, m, i, n, A+i, ld, sh->rs[i], tid);
    __syncthreads();
  }
}

// ---- per-shape drivers ----
__device__ void svd_tall(int wantU, int wantVT, Sh* sh, int tid){ // 128 x 71
  rl* MA=g_ws+O_MA; rl* MB=g_ws+O_MB; rl* MU=g_ws+O_MU; rl* MVT=g_ws+O_MVT;
  rl* SUB=g_ws+O_SUB; rl* SVTB=g_ws+O_SVTB;
  for(int w=tid;w<LDA*NSV;w+=NT) MB[w]=MA[w];
  __syncthreads();
  gebd2_upper(MB, LDA, 128, NSV, sh, tid);
  dbdsdc_U(NSV, wantU, sh, tid);
  if(wantU){
    for(int w=tid;w<128*NSV;w+=NT){ int c=w/128, r2=w-c*128; MU[r2+(size_t)LDA*c]=(r2<NSV)? SUB[r2+(size_t)LDV*c]:0.0; }
    __syncthreads();
    for(int i=NSV-1;i>=0;--i){
      if(sh->tq[i]!=0.0) app_left(MU, LDA, i, 128, 0, NSV, MB+(size_t)LDA*i, sh->tq[i], tid);
      __syncthreads();
    }
  }
  if(wantVT){
    for(int w=tid;w<LDV*NSV;w+=NT) MVT[w]=SVTB[w];
    __syncthreads();
    for(int i=NSV-2;i>=0;--i){
      if(sh->tp[i]!=0.0) app_right(MVT, LDV, 0, NSV, i+1, NSV, MB+i, LDA, sh->tp[i], tid);
      __syncthreads();
    }
  }
}
__device__ void svd_mid(Sh* sh, int tid){ // 64 x 71, wantU=0, wantVT=1
  rl* MA=g_ws+O_MA; rl* MB=g_ws+O_MB; rl* MVT=g_ws+O_MVT;
  rl* SVTB=g_ws+O_SVTB;
  for(int w=tid;w<LDA*NSV;w+=NT) MB[w]=MA[w];
  __syncthreads();
  gebd2_lower(MB, LDA, 64, NSV, sh, tid);
  dbdsdc_L(64, 0, sh, tid);
  for(int w=tid;w<64*NSV;w+=NT){ int c=w/64, r2=w-c*64; MVT[r2+(size_t)LDV*c]=(c<64)? SVTB[r2+(size_t)LDV*c]:0.0; }
  __syncthreads();
  for(int i=63;i>=0;--i){
    if(sh->tp[i]!=0.0) app_right(MVT, LDV, 0, 64, i, NSV, MB+i, LDA, sh->tp[i], tid);
    __syncthreads();
  }
}
__device__ void svd_wide(int m, Sh* sh, int tid){ // m x 71, m in {2,4,8,16,32}; wantU=0, wantVT=1
  rl* MA=g_ws+O_MA; rl* MB=g_ws+O_MB; rl* MQ=g_ws+O_MQ; rl* MVT=g_ws+O_MVT;
  rl* SVTB=g_ws+O_SVTB; rl* TB=g_ws+O_TB; rl* VT2=g_ws+O_VT2;
  for(int w=tid;w<LDA*NSV;w+=NT) MB[w]=MA[w];
  __syncthreads();
  gelq2(MB, LDA, m, NSV, sh, tid);
  for(int w=tid;w<m*NSV;w+=NT){ int c=w/m, r2=w-c*m; MQ[r2+(size_t)LDA*c]=(r2==c)?1.0:0.0; }
  __syncthreads();
  for(int j=m-1;j>=0;--j){
    if(sh->rs[j]!=0.0) app_right(MQ, LDA, 0, m, j, NSV, MB+j, LDA, sh->rs[j], tid);
    __syncthreads();
  }
  for(int w=tid;w<m*m;w+=NT){ int c=w/m, r2=w-c*m; TB[r2+(size_t)LDV*c]=(r2>=c)? MB[r2+(size_t)LDA*c]:0.0; }
  __syncthreads();
  gebd2_upper(TB, LDV, m, m, sh, tid);
  dbdsdc_U(m, 0, sh, tid);
  for(int w=tid;w<m*m;w+=NT){ int c=w/m, r2=w-c*m; VT2[r2+(size_t)LDV*c]=SVTB[r2+(size_t)LDV*c]; }
  __syncthreads();
  for(int i=m-2;i>=0;--i){
    if(sh->tp[i]!=0.0) app_right(VT2, LDV, 0, m, i+1, m, TB+i, LDV, sh->tp[i], tid);
    __syncthreads();
  }
  for(int w=tid;w<m*NSV;w+=NT){
    int c=w/m, r2=w-c*m;
    rl acc=0.0;
    for(int t=0;t<m;++t) acc += VT2[r2+(size_t)LDV*t]*MQ[t+(size_t)LDA*c];
    MVT[r2+(size_t)LDV*c]=acc;
  }
  __syncthreads();
}

// ---- main kernel ----
__global__ __launch_bounds__(NT)
void mps_kernel(const float* __restrict__ ch, const float* __restrict__ ci,
                const float* __restrict__ ictx, const int* __restrict__ tok)
{
  __shared__ Sh sh;
  int tid = threadIdx.x;
  rl* MA = g_ws + O_MA; rl* MU = g_ws + O_MU; rl* MVT = g_ws + O_MVT;
  int kprev = 0;
  for(int s=0;s<9;++s){
    if(tid==0){
      rl W00=ch[s*4+0], W01=ch[s*4+1], W10=ch[s*4+2], W11=ch[s*4+3];
      rl P00=1,P01=0,P10=0,P11=1;
      for(int mexp=0;mexp<=70;++mexp){
        int j=70-mexp;
        rl v0,v1;
        if(j==0){ v0=ictx[s*2+0]; v1=ictx[s*2+1]; }
        else{
          int b=(tok[j-1]>>(15-s))&1;
          v0=ci[s*4+b]; v1=ci[s*4+2+b];
        }
        g_ws[O_COLS + 0 + 2*j] = P00*v0+P01*v1;
        g_ws[O_COLS + 1 + 2*j] = P10*v0+P11*v1;
        rl n00=W00*P00+W01*P10, n01=W00*P01+W01*P11;
        rl n10=W10*P00+W11*P10, n11=W10*P01+W11*P11;
        P00=n00;P01=n01;P10=n10;P11=n11;
      }
    }
    __syncthreads();
    int m = (s==0)?2:2*kprev;
    for(int w=tid; w<m*NSV; w+=NT){
      int j=w/m, r2=w-j*m;
      int l=r2>>1, dd2=r2&1;
      rl cv = g_ws[O_COLS + dd2 + 2*j];
      MA[r2+(size_t)LDA*j] = (s==0)? cv : g_ws[O_CAR + l + 64*j]*cv;
    }
    __syncthreads();
    int wantU = (s==8)?1:0;
    if(m==128) svd_tall(wantU, wantU?0:1, &sh, tid);
    else if(m==64) svd_mid(&sh, tid);
    else svd_wide(m, &sh, tid);
    int k = min(64, min(m, NSV));
    __syncthreads();
    if(s<8){
      for(int w=tid; w<k*NSV; w+=NT){
        int j=w/k, l=w-j*k;
        g_ws[O_CAR + l + 64*j] = sh.d[l]*MVT[l+(size_t)LDV*j];
      }
    }
    __syncthreads();
    if(s==8){
      if(tid==0){
        rl W00=ch[8*4+0], W01=ch[8*4+1], W10=ch[8*4+2], W11=ch[8*4+3];
        rl P00=1,P01=0,P10=0,P11=1;
        for(int it=0;it<30;++it){
          rl n00=W00*P00+W01*P10, n01=W00*P01+W01*P11;
          rl n10=W10*P00+W11*P10, n11=W10*P01+W11*P11;
          P00=n00;P01=n01;P10=n10;P11=n11;
        }
        sh.sc[0]=P00+P10; sh.sc[1]=P01+P11;
      }
      __syncthreads();
      for(int r2=tid; r2<64; r2+=NT){
        rl acc=0.0;
        for(int l=0;l<64;++l)
          acc += sh.sc[0]*MU[(2*l)+(size_t)LDA*r2] + sh.sc[1]*MU[(2*l+1)+(size_t)LDA*r2];
        g_ws[O_VEC + r2] = acc/188.0;
      }
    }
    kprev = k;
    __syncthreads();
  }
}

__global__ __launch_bounds__(NT)
void head_kernel(const float* __restrict__ hw, const float* __restrict__ hb,
                 float* __restrict__ out)
{
  __shared__ float v[64];
  int tid=threadIdx.x;
  if(tid<64) v[tid]=(float)g_ws[O_VEC + tid];
  __syncthreads();
  int i = blockIdx.x*NT + tid;
  if(i<VOCAB){
    const float4* row = (const float4*)(hw + (size_t)i*64);
    float acc=0.f;
    #pragma unroll
    for(int c4=0;c4<16;++c4){
      float4 r4=row[c4];
      acc += r4.x*v[4*c4] + r4.y*v[4*c4+1] + r4.z*v[4*c4+2] + r4.w*v[4*c4+3];
    }
    out[i]=acc+hb[i];
  }
}

extern "C" void kernel_launch(void* const* d_in, const int* in_sizes, int n_in,
                              void* d_out, int out_size, void* d_ws, size_t ws_size,
                              hipStream_t stream)
{
  const float* ch  = (const float*)d_in[0];
  const float* ci  = (const float*)d_in[1];
  const float* hw  = (const float*)d_in[2];
  const float* hb  = (const float*)d_in[3];
  const float* ict = (const float*)d_in[4];
  const int*   tk  = (const int*)d_in[5];
  (void)d_ws; (void)ws_size; (void)in_sizes; (void)n_in; (void)out_size;

  hipLaunchKernelGGL(mps_kernel, dim3(1), dim3(NT), 0, stream, ch, ci, ict, tk);
  hipLaunchKernelGGL(head_kernel, dim3((VOCAB+NT-1)/NT), dim3(NT), 0, stream,
                     hw, hb, (float*)d_out);
}

// Round 5
// 11824.483 us; speedup vs baseline: 4.5207x; 1.9370x over previous
//
#include <hip/hip_runtime.h>

typedef double rl;
#define NT 256
#define NSV 71
#define LDA 128
#define LDV 72
#define SML 25
#define VOCAB 128000
#define LP 27   // LDS leaf pitch
#define PB 129  // LDS pitch for bidiag working matrix (odd => minimal fp64 bank aliasing)

// fp32 LAPACK constants (reference is numpy sgesdd in float32)
#define EPS32 1.1920928955078125e-7
#define UNFL32 1.17549435e-38

// g_ws offsets (doubles)
#define O_CAR   0
#define O_COLS  4608
#define O_VEC   4800
#define O_MA    5120
#define O_MU    23552
#define O_MQ    32768
#define O_MVT   41984
#define O_SUB   47168
#define O_SVTB  52352
#define O_U2    57536
#define O_VT2   62720
#define O_QU    67904
#define O_QV    73088
#define O_TB    78272

__device__ double g_ws[84000];

struct Sh {
  rl d[72], e[72], tq[72], tp[72], rc[72], rs[72];
  rl dsig[72], zz[72], zh[72], sigm[72], vals[72];
  rl ta[72], tb[72];
  rl b1[72], b2[72], b3[72], b4[72];
  rl LVT[26*LP], LU[26*LP];
  int srcU[72], srcVT[72], perm[72];
  int ia[72], ib[72], ic[72];
  int opk[12], opf[12], opa[12], opb[12], opq[12];
  rl sc[8];
  int si[16];
};

__device__ __forceinline__ rl d_sign(rl a, rl b){ return (b >= 0.0) ? fabs(a) : -fabs(a); }
__device__ __forceinline__ rl dlapy2(rl x, rl y){
  rl ax=fabs(x), ay=fabs(y);
  rl w = ax>ay?ax:ay, z = ax>ay?ay:ax;
  if(z==0.0) return w;
  rl t = z/w; return w*sqrt(1.0+t*t);
}
// LAPACK >= 3.10 dlartg convention (modern OpenBLAS)
__device__ void dlartg(rl f, rl g, rl* cs, rl* sn, rl* r){
  if(g==0.0){ *cs=1.0; *sn=0.0; *r=f; }
  else if(f==0.0){ *cs=0.0; *sn=d_sign(1.0,g); *r=fabs(g); }
  else{
    rl dd = sqrt(f*f+g*g);
    *cs = fabs(f)/dd;
    *r  = d_sign(dd, f);
    *sn = g/(*r);
  }
}

__device__ void dlas2(rl f, rl g, rl h, rl* ssmin, rl* ssmax){
  rl fa=fabs(f), ga=fabs(g), ha=fabs(h);
  rl fhmn=fmin(fa,ha), fhmx=fmax(fa,ha);
  if(fhmn==0.0){
    *ssmin=0.0;
    if(fhmx==0.0) *ssmax=ga;
    else { rl mx=fmax(fhmx,ga), mn=fmin(fhmx,ga); rl q=mn/mx; *ssmax=mx*sqrt(1.0+q*q); }
  } else {
    if(ga < fhmx){
      rl as=1.0+fhmn/fhmx, at=(fhmx-fhmn)/fhmx;
      rl au=(ga/fhmx); au=au*au;
      rl c=2.0/(sqrt(as*as+au)+sqrt(at*at+au));
      *ssmin=fhmn*c; *ssmax=fhmx/c;
    } else {
      rl au=fhmx/ga;
      if(au==0.0){ *ssmin=(fhmn*fhmx)/ga; *ssmax=ga; }
      else{
        rl as=1.0+fhmn/fhmx, at=(fhmx-fhmn)/fhmx;
        rl c=1.0/(sqrt(1.0+(as*au)*(as*au))+sqrt(1.0+(at*au)*(at*au)));
        *ssmin=(fhmn*c)*au; *ssmin=*ssmin+*ssmin;
        *ssmax=ga/(c+c);
      }
    }
  }
}

__device__ void dlasv2(rl f, rl g, rl h, rl* ssmin, rl* ssmax, rl* snr, rl* csr, rl* snl, rl* csl){
  rl ft=f, fa=fabs(f), ht=h, ha=fabs(h);
  int pmax=1;
  bool swp = (ha > fa);
  if(swp){ pmax=3; rl t=ft; ft=ht; ht=t; t=fa; fa=ha; ha=t; }
  rl gt=g, ga=fabs(g);
  rl clt=0, crt=0, slt=0, srt=0;
  if(ga==0.0){ *ssmin=ha; *ssmax=fa; clt=1.0; crt=1.0; slt=0.0; srt=0.0; }
  else{
    bool gasmal=true;
    if(ga > fa){
      pmax=2;
      if((fa/ga) < EPS32){
        gasmal=false;
        *ssmax=ga;
        if(ha>1.0) *ssmin=fa/(ga/ha); else *ssmin=(fa/ga)*ha;
        clt=1.0; slt=ht/gt; srt=1.0; crt=ft/gt;
      }
    }
    if(gasmal){
      rl dd=fa-ha;
      rl lv = (dd==fa) ? 1.0 : dd/fa;
      rl mq = gt/ft;
      rl tv = 2.0-lv;
      rl mm = mq*mq, tt = tv*tv;
      rl sv = sqrt(tt+mm);
      rl rv = (lv==0.0) ? fabs(mq) : sqrt(lv*lv+mm);
      rl a = 0.5*(sv+rv);
      *ssmin = ha/a; *ssmax = fa*a;
      rl t3;
      if(mm==0.0){
        if(lv==0.0) t3 = d_sign(2.0, ft)*d_sign(1.0, gt);
        else t3 = gt/d_sign(dd, ft) + mq/tv;
      } else {
        t3 = (mq/(sv+tv) + mq/(rv+lv))*(1.0+a);
      }
      rl l2 = sqrt(t3*t3+4.0);
      crt = 2.0/l2; srt = t3/l2;
      clt = (crt + srt*mq)/a;
      slt = (ht/ft)*srt/a;
    }
  }
  if(swp){ *csl=srt; *snl=crt; *csr=slt; *snr=clt; }
  else  { *csl=clt; *snl=slt; *csr=crt; *snr=srt; }
  rl tsign=1.0;
  if(pmax==1) tsign = d_sign(1.0,*csr)*d_sign(1.0,*csl)*d_sign(1.0,f);
  if(pmax==2) tsign = d_sign(1.0,*snr)*d_sign(1.0,*csl)*d_sign(1.0,g);
  if(pmax==3) tsign = d_sign(1.0,*snr)*d_sign(1.0,*snl)*d_sign(1.0,h);
  *ssmax = d_sign(*ssmax, tsign);
  *ssmin = d_sign(*ssmin, tsign*d_sign(1.0,f)*d_sign(1.0,h));
}

// Householder apply, order-preserving unroll-4 (grouped loads, sequential adds:
// bit-identical to the scalar loop).
__device__ __forceinline__ void app_left(rl* A, int ld, int r0, int m, int c0, int n, const rl* vbase, rl tau, int tid){
  const int len = m - r0 - 1;
  const rl* v = vbase + r0 + 1;
  for(int c=c0+tid; c<n; c+=NT){
    rl* col = A + (size_t)ld*c + r0;
    rl s = col[0];
    int i=0;
    for(; i+4<=len; i+=4){
      rl a0=col[1+i],a1=col[2+i],a2=col[3+i],a3=col[4+i];
      rl b0=v[i],b1=v[i+1],b2=v[i+2],b3=v[i+3];
      s+=a0*b0; s+=a1*b1; s+=a2*b2; s+=a3*b3;
    }
    for(; i<len; ++i) s += col[1+i]*v[i];
    rl w = s*tau;
    col[0] -= w;
    i=0;
    for(; i+4<=len; i+=4){
      rl b0=v[i],b1=v[i+1],b2=v[i+2],b3=v[i+3];
      col[1+i]-=w*b0; col[2+i]-=w*b1; col[3+i]-=w*b2; col[4+i]-=w*b3;
    }
    for(; i<len; ++i) col[1+i] -= w*v[i];
  }
}
__device__ __forceinline__ void app_right(rl* A, int ld, int r0, int m, int c0, int n, const rl* vbase, int vstride, rl tau, int tid){
  const int len = n - c0 - 1;
  const rl* v = vbase + (size_t)vstride*(c0+1);
  for(int r=r0+tid; r<m; r+=NT){
    rl* row = A + r + (size_t)ld*c0;
    rl s = row[0];
    int i=0;
    for(; i+4<=len; i+=4){
      rl a0=row[(size_t)ld*(1+i)], a1=row[(size_t)ld*(2+i)], a2=row[(size_t)ld*(3+i)], a3=row[(size_t)ld*(4+i)];
      rl b0=v[(size_t)vstride*i], b1=v[(size_t)vstride*(i+1)], b2=v[(size_t)vstride*(i+2)], b3=v[(size_t)vstride*(i+3)];
      s+=a0*b0; s+=a1*b1; s+=a2*b2; s+=a3*b3;
    }
    for(; i<len; ++i) s += row[(size_t)ld*(1+i)]*v[(size_t)vstride*i];
    rl w = s*tau;
    row[0] -= w;
    i=0;
    for(; i+4<=len; i+=4){
      rl b0=v[(size_t)vstride*i], b1=v[(size_t)vstride*(i+1)], b2=v[(size_t)vstride*(i+2)], b3=v[(size_t)vstride*(i+3)];
      row[(size_t)ld*(1+i)]-=w*b0; row[(size_t)ld*(2+i)]-=w*b1; row[(size_t)ld*(3+i)]-=w*b2; row[(size_t)ld*(4+i)]-=w*b3;
    }
    for(; i<len; ++i) row[(size_t)ld*(1+i)] -= w*v[(size_t)vstride*i];
  }
}

// ---- cooperative dbdsqr on LDS leaf blocks ----
__device__ void bdsqr_coop(int n, rl* d, rl* e, int ncvt, int nru, Sh* sh, int tid){
  if(n>1){
    rl eps=EPS32, unfl=UNFL32;
    rl tolmul=fmax(10.0,fmin(100.0,pow(eps,-0.125)));
    rl tol=tolmul*eps;
    rl thresh=0.0;
    int mm=n-1, oldll=-2, oldm=-2, idir=0, iter=0, maxit=6*n*n;
    if(tid==0){
      rl sminoa=fabs(d[0]);
      if(sminoa!=0.0){
        rl mu=sminoa;
        for(int i=1;i<n;++i){ mu=fabs(d[i])*(mu/(mu+fabs(e[i-1]))); sminoa=fmin(sminoa,mu); if(sminoa==0.0)break; }
      }
      sminoa=sminoa/sqrt((rl)n);
      thresh=fmax(tol*sminoa,(rl)(6*n*n)*unfl);
    }
    while(true){
      if(tid==0){
        int act=0, p_lo=0, p_cnt=0, p_fwd=1, p_mm=0;
        while(mm>0){
          if(iter>maxit) break;
          rl smax=fabs(d[mm]), smin=smax;
          int ll=-1;
          for(int lll=mm-1;lll>=0;--lll){
            rl abss=fabs(d[lll]), abse=fabs(e[lll]);
            if(abse<=thresh){ ll=lll; break; }
            smin=fmin(smin,abss);
            smax=fmax(smax,fmax(abss,abse));
          }
          if(ll==mm-1){ e[ll]=0.0; mm=mm-1; continue; }
          if(ll>=0) e[ll]=0.0;
          int lo=ll+1;
          if(mm==lo+1){
            rl sigmn,sigmx,sinr,cosr,sinl,cosl;
            dlasv2(d[lo],e[lo],d[mm],&sigmn,&sigmx,&sinr,&cosr,&sinl,&cosl);
            d[lo]=sigmx; d[mm]=sigmn; e[lo]=0.0;
            sh->sc[0]=cosr; sh->sc[1]=sinr; sh->sc[2]=cosl; sh->sc[3]=sinl;
            act=2; p_lo=lo; p_mm=mm;
            mm-=2;
            break;
          }
          if(lo>oldm || mm<oldll) idir=(fabs(d[lo])>=fabs(d[mm]))?1:2;
          rl sminl=0.0; int conv=0;
          if(idir==1){
            if(fabs(e[mm-1])<=tol*fabs(d[mm])){ e[mm-1]=0.0; conv=1; }
            if(!conv){
              rl mu=fabs(d[lo]); sminl=mu;
              for(int lll=lo;lll<mm;++lll){
                if(fabs(e[lll])<=tol*mu){ e[lll]=0.0; conv=1; break; }
                mu=fabs(d[lll+1])*(mu/(mu+fabs(e[lll])));
                sminl=fmin(sminl,mu);
              }
            }
          } else {
            if(fabs(e[lo])<=tol*fabs(d[lo])){ e[lo]=0.0; conv=1; }
            if(!conv){
              rl mu=fabs(d[mm]); sminl=mu;
              for(int lll=mm-1;lll>=lo;--lll){
                if(fabs(e[lll])<=tol*mu){ e[lll]=0.0; conv=1; break; }
                mu=fabs(d[lll])*(mu/(mu+fabs(e[lll])));
                sminl=fmin(sminl,mu);
              }
            }
          }
          if(conv) continue;
          oldll=lo; oldm=mm;
          rl shift=0.0, rr_;
          if(!((rl)n*tol*(sminl/smax) <= fmax(eps, 0.01*tol))){
            rl sll;
            if(idir==1){ sll=fabs(d[lo]); dlas2(d[mm-1],e[mm-1],d[mm],&shift,&rr_); }
            else { sll=fabs(d[mm]); dlas2(d[lo],e[lo],d[lo+1],&shift,&rr_); }
            if(sll>0.0){ rl q=shift/sll; if(q*q<eps) shift=0.0; }
          }
          iter += mm-lo;
          int cnt=mm-lo;
          if(shift==0.0){
            if(idir==1){
              rl cs=1.0, oldcs=1.0, sn=0.0, oldsn=0.0, r;
              for(int i=lo;i<mm;++i){
                dlartg(d[i]*cs,e[i],&cs,&sn,&r);
                if(i>lo) e[i-1]=oldsn*r;
                dlartg(oldcs*r, d[i+1]*sn, &oldcs,&oldsn,&d[i]);
                sh->b1[i-lo]=cs; sh->b2[i-lo]=sn; sh->b3[i-lo]=oldcs; sh->b4[i-lo]=oldsn;
              }
              rl h=d[mm]*cs; d[mm]=h*oldcs; e[mm-1]=h*oldsn;
              p_fwd=1;
              if(fabs(e[mm-1])<=thresh) e[mm-1]=0.0;
            } else {
              rl cs=1.0, oldcs=1.0, sn=0.0, oldsn=0.0, r;
              for(int i=mm;i>lo;--i){
                dlartg(d[i]*cs,e[i-1],&cs,&sn,&r);
                if(i<mm) e[i]=oldsn*r;
                dlartg(oldcs*r,d[i-1]*sn,&oldcs,&oldsn,&d[i]);
                int j=i-lo-1;
                sh->b1[j]=oldcs; sh->b2[j]=-oldsn; sh->b3[j]=cs; sh->b4[j]=-sn;
              }
              rl h=d[lo]*cs; d[lo]=h*oldcs; e[lo]=h*oldsn;
              p_fwd=0;
              if(fabs(e[lo])<=thresh) e[lo]=0.0;
            }
          } else {
            if(idir==1){
              rl f2=(fabs(d[lo])-shift)*(d_sign(1.0,d[lo])+shift/d[lo]);
              rl g2=e[lo], r, cosr,sinr,cosl,sinl;
              for(int i=lo;i<mm;++i){
                dlartg(f2,g2,&cosr,&sinr,&r);
                if(i>lo) e[i-1]=r;
                f2=cosr*d[i]+sinr*e[i];
                e[i]=cosr*e[i]-sinr*d[i];
                g2=sinr*d[i+1];
                d[i+1]=cosr*d[i+1];
                dlartg(f2,g2,&cosl,&sinl,&r);
                d[i]=r;
                f2=cosl*e[i]+sinl*d[i+1];
                d[i+1]=cosl*d[i+1]-sinl*e[i];
                if(i<mm-1){ g2=sinl*e[i+1]; e[i+1]=cosl*e[i+1]; }
                sh->b1[i-lo]=cosr; sh->b2[i-lo]=sinr; sh->b3[i-lo]=cosl; sh->b4[i-lo]=sinl;
              }
              e[mm-1]=f2;
              p_fwd=1;
              if(fabs(e[mm-1])<=thresh) e[mm-1]=0.0;
            } else {
              rl f2=(fabs(d[mm])-shift)*(d_sign(1.0,d[mm])+shift/d[mm]);
              rl g2=e[mm-1], r, cosr,sinr,cosl,sinl;
              for(int i=mm;i>lo;--i){
                dlartg(f2,g2,&cosr,&sinr,&r);
                if(i<mm) e[i]=r;
                f2=cosr*d[i]+sinr*e[i-1];
                e[i-1]=cosr*e[i-1]-sinr*d[i];
                g2=sinr*d[i-1];
                d[i-1]=cosr*d[i-1];
                dlartg(f2,g2,&cosl,&sinl,&r);
                d[i]=r;
                f2=cosl*e[i-1]+sinl*d[i-1];
                d[i-1]=cosl*d[i-1]-sinl*e[i-1];
                if(i>lo+1){ g2=sinl*e[i-2]; e[i-2]=cosl*e[i-2]; }
                int j=i-lo-1;
                sh->b1[j]=cosl; sh->b2[j]=-sinl; sh->b3[j]=cosr; sh->b4[j]=-sinr;
              }
              e[lo]=f2;
              p_fwd=0;
              if(fabs(e[lo])<=thresh) e[lo]=0.0;
            }
          }
          act=1; p_lo=lo; p_cnt=cnt;
          break;
        }
        sh->si[7]=act; sh->si[8]=p_lo; sh->si[9]=p_cnt; sh->si[10]=p_fwd; sh->si[11]=p_mm;
      }
      __syncthreads();
      int act=sh->si[7];
      if(act==0) break;
      if(act==1){
        int lo=sh->si[8], cnt=sh->si[9], fwd=sh->si[10];
        if(tid<ncvt){
          int k=tid;
          if(fwd){
            for(int j=0;j<cnt;++j){
              rl c=sh->b1[j], s=sh->b2[j];
              rl t=sh->LVT[(lo+j+1)*LP+k];
              sh->LVT[(lo+j+1)*LP+k]=c*t-s*sh->LVT[(lo+j)*LP+k];
              sh->LVT[(lo+j)*LP+k]=s*t+c*sh->LVT[(lo+j)*LP+k];
            }
          } else {
            for(int j=cnt-1;j>=0;--j){
              rl c=sh->b1[j], s=sh->b2[j];
              rl t=sh->LVT[(lo+j+1)*LP+k];
              sh->LVT[(lo+j+1)*LP+k]=c*t-s*sh->LVT[(lo+j)*LP+k];
              sh->LVT[(lo+j)*LP+k]=s*t+c*sh->LVT[(lo+j)*LP+k];
            }
          }
        } else if(tid<ncvt+nru){
          int r2=tid-ncvt;
          if(fwd){
            for(int j=0;j<cnt;++j){
              rl c=sh->b3[j], s=sh->b4[j];
              rl t=sh->LU[r2*LP+(lo+j+1)];
              sh->LU[r2*LP+(lo+j+1)]=c*t-s*sh->LU[r2*LP+(lo+j)];
              sh->LU[r2*LP+(lo+j)]=s*t+c*sh->LU[r2*LP+(lo+j)];
            }
          } else {
            for(int j=cnt-1;j>=0;--j){
              rl c=sh->b3[j], s=sh->b4[j];
              rl t=sh->LU[r2*LP+(lo+j+1)];
              sh->LU[r2*LP+(lo+j+1)]=c*t-s*sh->LU[r2*LP+(lo+j)];
              sh->LU[r2*LP+(lo+j)]=s*t+c*sh->LU[r2*LP+(lo+j)];
            }
          }
        }
      } else {
        int lo=sh->si[8], m2=sh->si[11];
        rl cosr=sh->sc[0], sinr=sh->sc[1], cosl=sh->sc[2], sinl=sh->sc[3];
        if(tid<ncvt){
          rl x=sh->LVT[lo*LP+tid], y=sh->LVT[m2*LP+tid];
          sh->LVT[lo*LP+tid]=cosr*x+sinr*y; sh->LVT[m2*LP+tid]=cosr*y-sinr*x;
        } else if(tid<ncvt+nru){
          int r2=tid-ncvt;
          rl x=sh->LU[r2*LP+lo], y=sh->LU[r2*LP+m2];
          sh->LU[r2*LP+lo]=cosl*x+sinl*y; sh->LU[r2*LP+m2]=cosl*y-sinl*x;
        }
      }
      __syncthreads();
    }
  }
  if(tid==0){
    for(int i=0;i<n;++i){ sh->ic[i]=(d[i]<0.0)?1:0; if(d[i]<0.0) d[i]=-d[i]; }
    int nsw=0;
    for(int i=0;i<n-1;++i){
      int isub=0; rl smin=d[0];
      for(int j=1;j<n-i;++j){ if(d[j]<=smin){ isub=j; smin=d[j]; } }
      int tgt=n-1-i;
      if(isub!=tgt){
        d[isub]=d[tgt]; d[tgt]=smin;
        sh->ia[nsw]=isub; sh->ib[nsw]=tgt; ++nsw;
      }
    }
    sh->si[7]=nsw;
  }
  __syncthreads();
  int nsw=sh->si[7];
  if(tid<ncvt){
    for(int i=0;i<n;++i) if(sh->ic[i]) sh->LVT[i*LP+tid]=-sh->LVT[i*LP+tid];
    for(int w2=0;w2<nsw;++w2){
      int a=sh->ia[w2], b=sh->ib[w2];
      rl t=sh->LVT[a*LP+tid]; sh->LVT[a*LP+tid]=sh->LVT[b*LP+tid]; sh->LVT[b*LP+tid]=t;
    }
  } else if(tid<ncvt+nru){
    int r2=tid-ncvt;
    for(int w2=0;w2<nsw;++w2){
      int a=sh->ia[w2], b=sh->ib[w2];
      rl t=sh->LU[r2*LP+a]; sh->LU[r2*LP+a]=sh->LU[r2*LP+b]; sh->LU[r2*LP+b]=t;
    }
  }
  __syncthreads();
}

// ---- leaf: dlasdq on LDS copies of the diagonal blocks ----
__device__ void leaf_exec(int f, int n, int sqre, int wantU, Sh* sh, int tid){
  rl* SVTB = g_ws + O_SVTB; rl* SUB = g_ws + O_SUB;
  int np = n + sqre;
  for(int w=tid; w<np*np; w+=NT){ int r2=w/np, c=w-r2*np; sh->LVT[r2*LP+c]=SVTB[(f+r2)+(size_t)LDV*(f+c)]; }
  if(wantU) for(int w=tid; w<n*n; w+=NT){ int r2=w/n, c=w-r2*n; sh->LU[r2*LP+c]=SUB[(f+r2)+(size_t)LDV*(f+c)]; }
  __syncthreads();
  if(sqre==1){
    if(tid==0){
      rl cs,snv,rv; rl* dd=sh->d+f; rl* ee=sh->e+f;
      for(int i=0;i<n;++i){
        dlartg(dd[i],ee[i],&cs,&snv,&rv);
        dd[i]=rv;
        if(i<n-1){ ee[i]=snv*dd[i+1]; dd[i+1]=cs*dd[i+1]; }
        else ee[i]=0.0;
        sh->b1[i]=cs; sh->b2[i]=snv;
      }
    }
    __syncthreads();
    if(tid<np){
      for(int j=0;j<n;++j){
        rl cj=sh->b1[j], sj=sh->b2[j];
        rl t=sh->LVT[(j+1)*LP+tid];
        sh->LVT[(j+1)*LP+tid]=cj*t-sj*sh->LVT[j*LP+tid];
        sh->LVT[j*LP+tid]=sj*t+cj*sh->LVT[j*LP+tid];
      }
    }
    __syncthreads();
    if(tid==0){
      rl cs,snv,rv; rl* dd=sh->d+f; rl* ee=sh->e+f;
      for(int i=0;i<n-1;++i){
        dlartg(dd[i],ee[i],&cs,&snv,&rv);
        dd[i]=rv; ee[i]=snv*dd[i+1]; dd[i+1]=cs*dd[i+1];
        sh->b1[i]=cs; sh->b2[i]=snv;
      }
    }
    __syncthreads();
    if(wantU && tid<n){
      for(int j=0;j<n-1;++j){
        rl cj=sh->b1[j], sj=sh->b2[j];
        rl t=sh->LU[tid*LP+(j+1)];
        sh->LU[tid*LP+(j+1)]=cj*t-sj*sh->LU[tid*LP+j];
        sh->LU[tid*LP+j]=sj*t+cj*sh->LU[tid*LP+j];
      }
    }
    __syncthreads();
  }
  bdsqr_coop(n, sh->d+f, sh->e+f, np, wantU? n:0, sh, tid);
  for(int w=tid; w<np*np; w+=NT){ int r2=w/np, c=w-r2*np; SVTB[(f+r2)+(size_t)LDV*(f+c)]=sh->LVT[r2*LP+c]; }
  if(wantU) for(int w=tid; w<n*n; w+=NT){ int r2=w/n, c=w-r2*n; SUB[(f+r2)+(size_t)LDV*(f+c)]=sh->LU[r2*LP+c]; }
  __syncthreads();
}

// ---- D&C merge (dlasd1/2/3) ----
__device__ void lasd1_merge(int f, int nl, int nr, int sqre, int wantU, Sh* sh, int tid){
  rl* SUB = g_ws + O_SUB; rl* SVTB = g_ws + O_SVTB;
  rl* U2 = g_ws + O_U2; rl* VT2 = g_ws + O_VT2; rl* QU = g_ws + O_QU; rl* QV = g_ws + O_QV;
  int n = nl+nr+1, m = n+sqre;
  if(tid==0){
    rl alpha = sh->d[f+nl], beta = sh->e[f+nl];
    sh->vals[0]=0.0;
    sh->zz[0] = alpha*SVTB[(f+nl)+(size_t)LDV*(f+nl)];
    sh->srcU[0]=-1; sh->srcVT[0]=f+nl;
    for(int i=0;i<nl;++i){
      sh->vals[1+i]=sh->d[f+i];
      sh->zz[1+i]=alpha*SVTB[(f+i)+(size_t)LDV*(f+nl)];
      sh->srcU[1+i]=f+i; sh->srcVT[1+i]=f+i;
    }
    for(int j=0;j<nr;++j){
      sh->vals[1+nl+j]=sh->d[f+nl+1+j];
      sh->zz[1+nl+j]=beta*SVTB[(f+nl+1+j)+(size_t)LDV*(f+nl+1)];
      sh->srcU[1+nl+j]=f+nl+1+j; sh->srcVT[1+nl+j]=f+nl+1+j;
    }
    sh->sc[0]=alpha; sh->sc[1]=beta;
    if(sqre==1){
      rl zM = beta*SVTB[(f+n)+(size_t)LDV*(f+nl+1)];
      rl c,s,r2;
      dlartg(sh->zz[0], zM, &c, &s, &r2);
      sh->zz[0]=r2; sh->sc[2]=c; sh->sc[3]=s;
    }
  }
  __syncthreads();
  if(sqre==1){
    rl c=sh->sc[2], s=sh->sc[3];
    int ra=f+nl, rb=f+n;
    for(int k=tid;k<m;k+=NT){
      size_t ci=(size_t)LDV*(f+k);
      rl a=SVTB[ra+ci], b=SVTB[rb+ci];
      SVTB[ra+ci]=c*a+s*b; SVTB[rb+ci]=-s*a+c*b;
    }
  }
  __syncthreads();
  if(tid==0){
    rl maxd=0.0; for(int i=0;i<n;++i) maxd=fmax(maxd,fabs(sh->vals[i]));
    rl tol = 8.0*EPS32*fmax(maxd, fmax(fabs(sh->sc[0]), fabs(sh->sc[1])));
    int nds=0;
    sh->ic[nds++]=0;
    for(int i=1;i<n;++i) if(fabs(sh->zz[i]) > tol) sh->ic[nds++]=i;
    for(int a=1;a<nds;++a){
      int key=sh->ic[a]; rl kv=sh->vals[key]; int b=a-1;
      while(b>=1 && sh->vals[sh->ic[b]] > kv){ sh->ic[b+1]=sh->ic[b]; --b; }
      sh->ic[b+1]=key;
    }
    int K=nds, pos=nds;
    for(int i=1;i<n;++i) if(fabs(sh->zz[i]) <= tol) sh->ic[pos++]=i;
    for(int a=K+1;a<n;++a){
      int key=sh->ic[a]; rl kv=sh->vals[key]; int b=a-1;
      while(b>=K && sh->vals[sh->ic[b]] > kv){ sh->ic[b+1]=sh->ic[b]; --b; }
      sh->ic[b+1]=key;
    }
    for(int t=0;t<n;++t){ sh->ta[t]=sh->vals[t]; sh->tb[t]=sh->zz[t]; sh->ia[t]=sh->srcU[t]; sh->ib[t]=sh->srcVT[t]; }
    for(int t=0;t<n;++t){
      int p=sh->ic[t];
      sh->dsig[t]=sh->ta[p]; sh->zz[t]=sh->tb[p]; sh->srcU[t]=sh->ia[p]; sh->srcVT[t]=sh->ib[p];
    }
    rl rho=0.0; for(int t=0;t<K;++t){ rl zv=sh->zz[t]; rho += zv*zv; }
    sh->sc[4]=rho;
    sh->si[0]=K; sh->si[1]=n; sh->si[2]=m; sh->si[3]=f; sh->si[4]=nl;
  }
  __syncthreads();
  int K=sh->si[0], n_=sh->si[1], m_=sh->si[2], f_=sh->si[3], nl_=sh->si[4];
  if(wantU){
    for(int w=tid; w<n_*n_; w+=NT){
      int col=w/n_, row=w-col*n_;
      int su=sh->srcU[col];
      rl v;
      if(su<0) v = (row==nl_) ? 1.0 : 0.0;
      else v = SUB[(f_+row)+(size_t)LDV*su];
      U2[row+(size_t)LDV*col]=v;
    }
  }
  for(int w=tid; w<n_*m_; w+=NT){
    int row=w/m_, col=w-row*m_;
    VT2[row+(size_t)LDV*col] = SVTB[sh->srcVT[row]+(size_t)LDV*(f_+col)];
  }
  __syncthreads();
  rl rho=sh->sc[4];
  for(int j=tid;j<K;j+=NT){
    rl lo=sh->dsig[j];
    rl hi=(j<K-1)? sh->dsig[j+1] : sqrt(sh->dsig[K-1]*sh->dsig[K-1]+rho);
    for(int it=0; it<130; ++it){
      rl mid=0.5*(lo+hi);
      if(mid<=lo || mid>=hi) break;
      rl g=1.0;
      for(int i2=0;i2<K;++i2){
        rl zi=sh->zz[i2];
        g += zi*zi/((sh->dsig[i2]-mid)*(sh->dsig[i2]+mid));
      }
      if(g<0.0) lo=mid; else hi=mid;
    }
    sh->sigm[j]=0.5*(lo+hi);
  }
  __syncthreads();
  for(int i2=tid;i2<K;i2+=NT){
    rl di=sh->dsig[i2];
    rl p=(di - sh->sigm[K-1])*(di + sh->sigm[K-1]);
    for(int j=0;j<i2;++j)
      p *= (di - sh->sigm[j])*(di + sh->sigm[j])/((di - sh->dsig[j])*(di + sh->dsig[j]));
    for(int j=i2;j<K-1;++j)
      p *= (di - sh->sigm[j])*(di + sh->sigm[j])/((di - sh->dsig[j+1])*(di + sh->dsig[j+1]));
    sh->zh[i2] = d_sign(sqrt(fabs(p)), sh->zz[i2]);
  }
  __syncthreads();
  for(int j=tid;j<K;j+=NT){
    rl sj=sh->sigm[j];
    rl nu=0.0, nv=0.0;
    for(int i2=0;i2<K;++i2){
      rl di=sh->dsig[i2];
      rl vv=sh->zh[i2]/((di-sj)*(di+sj));
      QV[i2+(size_t)LDV*j]=vv; nv+=vv*vv;
      if(wantU){
        rl uu=(i2==0)? -1.0 : di*vv;
        QU[i2+(size_t)LDV*j]=uu; nu+=uu*uu;
      }
    }
    nv=1.0/sqrt(nv);
    for(int i2=0;i2<K;++i2) QV[i2+(size_t)LDV*j]*=nv;
    if(wantU){
      nu=1.0/sqrt(nu);
      for(int i2=0;i2<K;++i2) QU[i2+(size_t)LDV*j]*=nu;
    }
  }
  __syncthreads();
  if(tid==0){
    int nd2=n_-K;
    for(int t=0;t<nd2;++t) sh->ia[t]=K+t;
    int ps=K-1, pd=nd2-1;
    int t=0;
    while(t<n_){
      rl vs = (ps>=0)? sh->sigm[ps] : -1.0;
      rl vd = (pd>=0)? sh->dsig[sh->ia[pd]] : -1.0;
      if(vs >= vd){ sh->perm[t]=ps; sh->vals[t]=vs; --ps; }
      else { sh->perm[t]=1000+sh->ia[pd]; sh->vals[t]=vd; --pd; }
      ++t;
    }
    for(int q=0;q<n_;++q) sh->d[f_+q]=sh->vals[q];
  }
  __syncthreads();
  if(wantU){
    for(int w=tid; w<n_*n_; w+=NT){
      int t=w/n_, row=w-t*n_;
      int src=sh->perm[t];
      rl acc;
      if(src>=1000) acc = U2[row+(size_t)LDV*(src-1000)];
      else{
        const rl* urow = U2 + row;
        const rl* qcol = QU + (size_t)LDV*src;
        rl s=0.0; int i=0;
        for(; i+4<=K; i+=4){
          rl a0=urow[(size_t)LDV*i], a1=urow[(size_t)LDV*(i+1)], a2=urow[(size_t)LDV*(i+2)], a3=urow[(size_t)LDV*(i+3)];
          rl b0=qcol[i], b1=qcol[i+1], b2=qcol[i+2], b3=qcol[i+3];
          s+=a0*b0; s+=a1*b1; s+=a2*b2; s+=a3*b3;
        }
        for(; i<K; ++i) s += urow[(size_t)LDV*i]*qcol[i];
        acc=s;
      }
      SUB[(f_+row)+(size_t)LDV*(f_+t)] = acc;
    }
  }
  for(int w=tid; w<n_*m_; w+=NT){
    int t=w/m_, col=w-t*m_;
    int src=sh->perm[t];
    rl acc;
    if(src>=1000) acc = VT2[(src-1000)+(size_t)LDV*col];
    else{
      const rl* qcol = QV + (size_t)LDV*src;
      const rl* vcol = VT2 + (size_t)LDV*col;
      rl s=0.0; int i=0;
      for(; i+4<=K; i+=4){
        rl a0=qcol[i],a1=qcol[i+1],a2=qcol[i+2],a3=qcol[i+3];
        rl b0=vcol[i],b1=vcol[i+1],b2=vcol[i+2],b3=vcol[i+3];
        s+=a0*b0; s+=a1*b1; s+=a2*b2; s+=a3*b3;
      }
      for(; i<K; ++i) s += qcol[i]*vcol[i];
      acc=s;
    }
    SVTB[(f_+t)+(size_t)LDV*(f_+col)] = acc;
  }
  __syncthreads();
}

// ---- dlasd0: iterative post-order over the D&C tree ----
__device__ void run_dc(int n, int wantU, Sh* sh, int tid){
  if(tid==0){
    int sf[12], sn2[12], sq[12], sv[12]; int sp=0, no=0;
    sf[0]=0; sn2[0]=n; sq[0]=0; sv[0]=0; sp=1;
    while(sp>0){
      --sp;
      int f=sf[sp], nn=sn2[sp], q=sq[sp], v=sv[sp];
      if(nn<=SML){ sh->opk[no]=0; sh->opf[no]=f; sh->opa[no]=nn; sh->opq[no]=q; ++no; }
      else if(v==0){
        int nl=nn/2, nr=nn-nl-1;
        sf[sp]=f; sn2[sp]=nn; sq[sp]=q; sv[sp]=1; ++sp;
        sf[sp]=f+nl+1; sn2[sp]=nr; sq[sp]=q; sv[sp]=0; ++sp;
        sf[sp]=f; sn2[sp]=nl; sq[sp]=1; sv[sp]=0; ++sp;
      } else {
        int nl=nn/2, nr=nn-nl-1;
        sh->opk[no]=1; sh->opf[no]=f; sh->opa[no]=nl; sh->opb[no]=nr; sh->opq[no]=q; ++no;
      }
    }
    sh->si[6]=no;
  }
  __syncthreads();
  int no=sh->si[6];
  for(int o=0;o<no;++o){
    if(sh->opk[o]==0) leaf_exec(sh->opf[o], sh->opa[o], sh->opq[o], wantU, sh, tid);
    else lasd1_merge(sh->opf[o], sh->opa[o], sh->opb[o], sh->opq[o], wantU, sh, tid);
  }
}

__device__ void dbdsdc_U(int n, int wantU, Sh* sh, int tid){
  rl* SUB = g_ws + O_SUB; rl* SVTB = g_ws + O_SVTB;
  for(int w=tid; w<LDV*LDV; w+=NT){
    int c=w/LDV, r2=w-c*LDV; rl v=(r2==c)?1.0:0.0;
    SVTB[w]=v;
    if(wantU) SUB[w]=v;
  }
  __syncthreads();
  if(n <= SML) leaf_exec(0, n, 0, wantU, sh, tid);
  else run_dc(n, wantU, sh, tid);
}

__device__ void dbdsdc_L(int n, int wantU, Sh* sh, int tid){
  if(tid==0){
    for(int i=0;i<n-1;++i){
      rl cs,snv,rv;
      dlartg(sh->d[i], sh->e[i], &cs,&snv,&rv);
      sh->d[i]=rv; sh->e[i]=snv*sh->d[i+1]; sh->d[i+1]=cs*sh->d[i+1];
      sh->rc[i]=cs; sh->rs[i]=snv;
    }
  }
  __syncthreads();
  dbdsdc_U(n, wantU, sh, tid);
  if(wantU){
    rl* SUB = g_ws + O_SUB;
    for(int c=tid;c<n;c+=NT){
      size_t ci=(size_t)LDV*c;
      for(int k=n-2;k>=0;--k){
        rl a=SUB[k+ci], b=SUB[k+1+ci];
        SUB[k+ci]  = sh->rc[k]*a - sh->rs[k]*b;
        SUB[k+1+ci]= sh->rs[k]*a + sh->rc[k]*b;
      }
    }
  }
  __syncthreads();
}

// ---- Householder helpers (wave-parallel norm) ----
__device__ __forceinline__ void gen_reflect_col(rl* A, int ld, int i, int r0, int m, rl* outBeta, rl* outTau, Sh* sh, int tid){
  if(tid<64){
    rl ps=0.0;
    for(int r=r0+1+tid;r<m;r+=64){ rl v=A[r+(size_t)ld*i]; ps+=v*v; }
    for(int off=32;off>0;off>>=1) ps += __shfl_down(ps,off,64);
    if(tid==0){
      rl alpha=A[r0+(size_t)ld*i];
      rl xn=sqrt(ps);
      rl beta, tau, scl; int doscale;
      if(xn==0.0){ tau=0.0; beta=alpha; scl=0.0; doscale=0; }
      else{ beta=-d_sign(dlapy2(alpha,xn),alpha); tau=(beta-alpha)/beta; scl=1.0/(alpha-beta); doscale=1; }
      sh->sc[5]=beta; sh->sc[6]=tau; sh->sc[7]=scl; sh->si[5]=doscale;
    }
  }
  __syncthreads();
  if(sh->si[5]) for(int r=r0+1+tid;r<m;r+=NT) A[r+(size_t)ld*i]*=sh->sc[7];
  __syncthreads();
  if(tid==0){ *outBeta=sh->sc[5]; *outTau=sh->sc[6]; }
}
__device__ __forceinline__ void gen_reflect_row(rl* A, int ld, int i, int c0, int n, rl* outBeta, rl* outTau, Sh* sh, int tid){
  if(tid<64){
    rl ps=0.0;
    for(int c=c0+1+tid;c<n;c+=64){ rl v=A[i+(size_t)ld*c]; ps+=v*v; }
    for(int off=32;off>0;off>>=1) ps += __shfl_down(ps,off,64);
    if(tid==0){
      rl alpha=A[i+(size_t)ld*c0];
      rl xn=sqrt(ps);
      rl beta, tau, scl; int doscale;
      if(xn==0.0){ tau=0.0; beta=alpha; scl=0.0; doscale=0; }
      else{ beta=-d_sign(dlapy2(alpha,xn),alpha); tau=(beta-alpha)/beta; scl=1.0/(alpha-beta); doscale=1; }
      sh->sc[5]=beta; sh->sc[6]=tau; sh->sc[7]=scl; sh->si[5]=doscale;
    }
  }
  __syncthreads();
  if(sh->si[5]) for(int c=c0+1+tid;c<n;c+=NT) A[i+(size_t)ld*c]*=sh->sc[7];
  __syncthreads();
  if(tid==0){ *outBeta=sh->sc[5]; *outTau=sh->sc[6]; }
}

__device__ __forceinline__ void gebd2_upper(rl* A, int ld, int m, int n, Sh* sh, int tid){
  for(int i=0;i<n;++i){
    gen_reflect_col(A, ld, i, i, m, &sh->d[i], &sh->tq[i], sh, tid);
    __syncthreads();
    if(sh->tq[i]!=0.0) app_left(A, ld, i, m, i+1, n, A+(size_t)ld*i, sh->tq[i], tid);
    __syncthreads();
    if(i<n-1){
      gen_reflect_row(A, ld, i, i+1, n, &sh->e[i], &sh->tp[i], sh, tid);
      __syncthreads();
      if(sh->tp[i]!=0.0) app_right(A, ld, i+1, m, i+1, n, A+i, ld, sh->tp[i], tid);
      __syncthreads();
    } else { if(tid==0) sh->tp[i]=0.0; __syncthreads(); }
  }
}
__device__ __forceinline__ void gebd2_lower(rl* A, int ld, int m, int n, Sh* sh, int tid){
  for(int i=0;i<m;++i){
    gen_reflect_row(A, ld, i, i, n, &sh->d[i], &sh->tp[i], sh, tid);
    __syncthreads();
    if(sh->tp[i]!=0.0) app_right(A, ld, i+1, m, i, n, A+i, ld, sh->tp[i], tid);
    __syncthreads();
    if(i<m-1){
      gen_reflect_col(A, ld, i, i+1, m, &sh->e[i], &sh->tq[i], sh, tid);
      __syncthreads();
      if(sh->tq[i]!=0.0) app_left(A, ld, i+1, m, i+1, n, A+(size_t)ld*i, sh->tq[i], tid);
      __syncthreads();
    }
  }
}
__device__ __forceinline__ void gelq2(rl* A, int ld, int m, int n, Sh* sh, int tid){
  for(int i=0;i<m;++i){
    rl beta, tau;
    gen_reflect_row(A, ld, i, i, n, &beta, &tau, sh, tid);
    if(tid==0){ sh->rs[i]=sh->sc[6]; A[i+(size_t)ld*i]=sh->sc[5]; }
    __syncthreads();
    if(i<m-1 && sh->rs[i]!=0.0) app_right(A, ld, i+1, m, i, n, A+i, ld, sh->rs[i], tid);
    __syncthreads();
  }
}

// ---- per-shape drivers (MBL = LDS working matrix, pitch PB) ----
__device__ void svd_tall(int wantU, int wantVT, rl* MBL, Sh* sh, int tid){ // 128 x 71
  rl* MA=g_ws+O_MA; rl* MU=g_ws+O_MU; rl* MVT=g_ws+O_MVT;
  rl* SUB=g_ws+O_SUB; rl* SVTB=g_ws+O_SVTB;
  for(int w=tid;w<128*NSV;w+=NT){ int c=w>>7, r2=w&127; MBL[r2+(size_t)PB*c]=MA[r2+(size_t)LDA*c]; }
  __syncthreads();
  gebd2_upper(MBL, PB, 128, NSV, sh, tid);
  dbdsdc_U(NSV, wantU, sh, tid);
  if(wantU){
    for(int w=tid;w<128*NSV;w+=NT){ int c=w>>7, r2=w&127; MU[r2+(size_t)LDA*c]=(r2<NSV)? SUB[r2+(size_t)LDV*c]:0.0; }
    __syncthreads();
    for(int i=NSV-1;i>=0;--i){
      if(sh->tq[i]!=0.0) app_left(MU, LDA, i, 128, 0, NSV, MBL+(size_t)PB*i, sh->tq[i], tid);
      __syncthreads();
    }
  }
  if(wantVT){
    for(int w=tid;w<LDV*NSV;w+=NT) MVT[w]=SVTB[w];
    __syncthreads();
    for(int i=NSV-2;i>=0;--i){
      if(sh->tp[i]!=0.0) app_right(MVT, LDV, 0, NSV, i+1, NSV, MBL+i, PB, sh->tp[i], tid);
      __syncthreads();
    }
  }
}
__device__ void svd_mid(rl* MBL, Sh* sh, int tid){ // 64 x 71, wantU=0, wantVT=1
  rl* MA=g_ws+O_MA; rl* MVT=g_ws+O_MVT;
  rl* SVTB=g_ws+O_SVTB;
  for(int w=tid;w<64*NSV;w+=NT){ int c=w>>6, r2=w&63; MBL[r2+(size_t)PB*c]=MA[r2+(size_t)LDA*c]; }
  __syncthreads();
  gebd2_lower(MBL, PB, 64, NSV, sh, tid);
  dbdsdc_L(64, 0, sh, tid);
  for(int w=tid;w<64*NSV;w+=NT){ int c=w>>6, r2=w&63; MVT[r2+(size_t)LDV*c]=(c<64)? SVTB[r2+(size_t)LDV*c]:0.0; }
  __syncthreads();
  for(int i=63;i>=0;--i){
    if(sh->tp[i]!=0.0) app_right(MVT, LDV, 0, 64, i, NSV, MBL+i, PB, sh->tp[i], tid);
    __syncthreads();
  }
}
__device__ void svd_wide(int m, rl* MBL, Sh* sh, int tid){ // m x 71, m in {2,4,8,16,32}; wantU=0, wantVT=1
  rl* MA=g_ws+O_MA; rl* MQ=g_ws+O_MQ; rl* MVT=g_ws+O_MVT;
  rl* SVTB=g_ws+O_SVTB; rl* TB=g_ws+O_TB; rl* VT2=g_ws+O_VT2;
  for(int w=tid;w<m*NSV;w+=NT){ int c=w/m, r2=w-c*m; MBL[r2+(size_t)PB*c]=MA[r2+(size_t)LDA*c]; }
  __syncthreads();
  gelq2(MBL, PB, m, NSV, sh, tid);
  for(int w=tid;w<m*NSV;w+=NT){ int c=w/m, r2=w-c*m; MQ[r2+(size_t)LDA*c]=(r2==c)?1.0:0.0; }
  __syncthreads();
  for(int j=m-1;j>=0;--j){
    if(sh->rs[j]!=0.0) app_right(MQ, LDA, 0, m, j, NSV, MBL+j, PB, sh->rs[j], tid);
    __syncthreads();
  }
  for(int w=tid;w<m*m;w+=NT){ int c=w/m, r2=w-c*m; TB[r2+(size_t)LDV*c]=(r2>=c)? MBL[r2+(size_t)PB*c]:0.0; }
  __syncthreads();
  gebd2_upper(TB, LDV, m, m, sh, tid);
  dbdsdc_U(m, 0, sh, tid);
  for(int w=tid;w<m*m;w+=NT){ int c=w/m, r2=w-c*m; VT2[r2+(size_t)LDV*c]=SVTB[r2+(size_t)LDV*c]; }
  __syncthreads();
  for(int i=m-2;i>=0;--i){
    if(sh->tp[i]!=0.0) app_right(VT2, LDV, 0, m, i+1, m, TB+i, LDV, sh->tp[i], tid);
    __syncthreads();
  }
  for(int w=tid;w<m*NSV;w+=NT){
    int c=w/m, r2=w-c*m;
    const rl* vrow = VT2 + r2;
    const rl* qcol = MQ + (size_t)LDA*c;
    rl s=0.0; int t=0;
    for(; t+4<=m; t+=4){
      rl a0=vrow[(size_t)LDV*t], a1=vrow[(size_t)LDV*(t+1)], a2=vrow[(size_t)LDV*(t+2)], a3=vrow[(size_t)LDV*(t+3)];
      rl b0=qcol[t], b1=qcol[t+1], b2=qcol[t+2], b3=qcol[t+3];
      s+=a0*b0; s+=a1*b1; s+=a2*b2; s+=a3*b3;
    }
    for(; t<m; ++t) s += vrow[(size_t)LDV*t]*qcol[t];
    MVT[r2+(size_t)LDV*c]=s;
  }
  __syncthreads();
}

// ---- main kernel ----
__global__ __launch_bounds__(NT)
void mps_kernel(const float* __restrict__ ch, const float* __restrict__ ci,
                const float* __restrict__ ictx, const int* __restrict__ tok)
{
  __shared__ Sh sh;
  extern __shared__ rl MBL[];   // PB*NSV doubles (73272 B dynamic LDS)
  int tid = threadIdx.x;
  rl* MA = g_ws + O_MA; rl* MU = g_ws + O_MU; rl* MVT = g_ws + O_MVT;
  int kprev = 0;
  for(int s=0;s<9;++s){
    if(tid==0){
      rl W00=ch[s*4+0], W01=ch[s*4+1], W10=ch[s*4+2], W11=ch[s*4+3];
      rl P00=1,P01=0,P10=0,P11=1;
      for(int mexp=0;mexp<=70;++mexp){
        int j=70-mexp;
        rl v0,v1;
        if(j==0){ v0=ictx[s*2+0]; v1=ictx[s*2+1]; }
        else{
          int b=(tok[j-1]>>(15-s))&1;
          v0=ci[s*4+b]; v1=ci[s*4+2+b];
        }
        g_ws[O_COLS + 0 + 2*j] = P00*v0+P01*v1;
        g_ws[O_COLS + 1 + 2*j] = P10*v0+P11*v1;
        rl n00=W00*P00+W01*P10, n01=W00*P01+W01*P11;
        rl n10=W10*P00+W11*P10, n11=W10*P01+W11*P11;
        P00=n00;P01=n01;P10=n10;P11=n11;
      }
    }
    __syncthreads();
    int m = (s==0)?2:2*kprev;
    for(int w=tid; w<m*NSV; w+=NT){
      int j=w/m, r2=w-j*m;
      int l=r2>>1, dd2=r2&1;
      rl cv = g_ws[O_COLS + dd2 + 2*j];
      MA[r2+(size_t)LDA*j] = (s==0)? cv : g_ws[O_CAR + l + 64*j]*cv;
    }
    __syncthreads();
    int wantU = (s==8)?1:0;
    if(m==128) svd_tall(wantU, wantU?0:1, MBL, &sh, tid);
    else if(m==64) svd_mid(MBL, &sh, tid);
    else svd_wide(m, MBL, &sh, tid);
    int k = min(64, min(m, NSV));
    __syncthreads();
    if(s<8){
      for(int w=tid; w<k*NSV; w+=NT){
        int j=w/k, l=w-j*k;
        g_ws[O_CAR + l + 64*j] = sh.d[l]*MVT[l+(size_t)LDV*j];
      }
    }
    __syncthreads();
    if(s==8){
      if(tid==0){
        rl W00=ch[8*4+0], W01=ch[8*4+1], W10=ch[8*4+2], W11=ch[8*4+3];
        rl P00=1,P01=0,P10=0,P11=1;
        for(int it=0;it<30;++it){
          rl n00=W00*P00+W01*P10, n01=W00*P01+W01*P11;
          rl n10=W10*P00+W11*P10, n11=W10*P01+W11*P11;
          P00=n00;P01=n01;P10=n10;P11=n11;
        }
        sh.sc[0]=P00+P10; sh.sc[1]=P01+P11;
      }
      __syncthreads();
      for(int r2=tid; r2<64; r2+=NT){
        rl acc=0.0;
        for(int l=0;l<64;++l)
          acc += sh.sc[0]*MU[(2*l)+(size_t)LDA*r2] + sh.sc[1]*MU[(2*l+1)+(size_t)LDA*r2];
        g_ws[O_VEC + r2] = acc/188.0;
      }
    }
    kprev = k;
    __syncthreads();
  }
}

__global__ __launch_bounds__(NT)
void head_kernel(const float* __restrict__ hw, const float* __restrict__ hb,
                 float* __restrict__ out)
{
  __shared__ float v[64];
  int tid=threadIdx.x;
  if(tid<64) v[tid]=(float)g_ws[O_VEC + tid];
  __syncthreads();
  int i = blockIdx.x*NT + tid;
  if(i<VOCAB){
    const float4* row = (const float4*)(hw + (size_t)i*64);
    float acc=0.f;
    #pragma unroll
    for(int c4=0;c4<16;++c4){
      float4 r4=row[c4];
      acc += r4.x*v[4*c4] + r4.y*v[4*c4+1] + r4.z*v[4*c4+2] + r4.w*v[4*c4+3];
    }
    out[i]=acc+hb[i];
  }
}

extern "C" void kernel_launch(void* const* d_in, const int* in_sizes, int n_in,
                              void* d_out, int out_size, void* d_ws, size_t ws_size,
                              hipStream_t stream)
{
  const float* ch  = (const float*)d_in[0];
  const float* ci  = (const float*)d_in[1];
  const float* hw  = (const float*)d_in[2];
  const float* hb  = (const float*)d_in[3];
  const float* ict = (const float*)d_in[4];
  const int*   tk  = (const int*)d_in[5];
  (void)d_ws; (void)ws_size; (void)in_sizes; (void)n_in; (void)out_size;

  size_t dynls = (size_t)PB*NSV*sizeof(double);   // 73272 B
  hipLaunchKernelGGL(mps_kernel, dim3(1), dim3(NT), dynls, stream, ch, ci, ict, tk);
  hipLaunchKernelGGL(head_kernel, dim3((VOCAB+NT-1)/NT), dim3(NT), 0, stream,
                     hw, hb, (float*)d_out);
}